// Round 4
// baseline (470.052 us; speedup 1.0000x reference)
//
#include <hip/hip_runtime.h>

typedef _Float16 f16;
typedef f16 f16x2 __attribute__((ext_vector_type(2)));
typedef f16 f16x8 __attribute__((ext_vector_type(8)));
typedef float f32x4 __attribute__((ext_vector_type(4)));
typedef float f32x2 __attribute__((ext_vector_type(2)));

#define MFMA16(a, b, c) __builtin_amdgcn_mfma_f32_16x16x32_f16((a), (b), (c), 0, 0, 0)

static __device__ __forceinline__ f16x8 cvt8(const float* __restrict__ p) {
    f32x4 p0 = *(const f32x4*)p;
    f32x4 p1 = *(const f32x4*)(p + 4);
    f16x8 a;
    a[0] = (f16)p0[0]; a[1] = (f16)p0[1]; a[2] = (f16)p0[2]; a[3] = (f16)p0[3];
    a[4] = (f16)p1[0]; a[5] = (f16)p1[1]; a[6] = (f16)p1[2]; a[7] = (f16)p1[3];
    return a;
}

// Fused prep: blocks [0,48) repack weights to B-fragment order; [48,48+CB)
// count in-degrees; rest classify nodes by depth into recs[].x.
__global__ __launch_bounds__(256) void k_prep(
        const float* __restrict__ pw, const float* __restrict__ mw1,
        const float* __restrict__ mw2, const float* __restrict__ uw1,
        const float* __restrict__ uw2,
        f16* __restrict__ pwp, f16* __restrict__ mw1p, f16* __restrict__ mw2p,
        f16* __restrict__ uw1p, f16* __restrict__ uw2p,
        const int* __restrict__ ei, int* __restrict__ degv,
        const int* __restrict__ dep, int* __restrict__ dcnt,
        int4* __restrict__ recs, int CB, int E, int N) {
    __shared__ int lcnt[4];
    __shared__ int lbase[4];
    int b = blockIdx.x;
    int t = threadIdx.x;
    if (b < 48) {
        const float* W; f16* out; int fb;
        if (b < 8)       { W = pw;  out = pwp;  fb = b; }
        else if (b < 16) { W = mw1; out = mw1p; fb = b - 8; }
        else if (b < 24) { W = mw2; out = mw2p; fb = b - 16; }
        else if (b < 40) { W = uw1; out = uw1p; fb = b - 24; }
        else             { W = uw2; out = uw2p; fb = b - 40; }
        int idx = fb * 256 + t;
        int lane = idx & 63;
        int nt = (idx >> 6) & 7;
        int kt = idx >> 9;
        int colx = lane & 15, quad = lane >> 4;
        f16* o = out + (size_t)idx * 8;
        const float* wb = W + (size_t)(kt * 32 + quad * 8) * 128 + nt * 16 + colx;
#pragma unroll
        for (int j = 0; j < 8; j++) o[j] = (f16)wb[(size_t)j * 128];
    } else if (b < 48 + CB) {
        int e = (b - 48) * 256 + t;
        if (e < E) atomicAdd(&degv[ei[E + e]], 1);
    } else {
        if (t < 4) lcnt[t] = 0;
        __syncthreads();
        int v = (b - 48 - CB) * 256 + t;
        int d = (v < N) ? dep[v] : 0;
        int p = -1;
        if (d >= 1 && d <= 4) p = atomicAdd(&lcnt[d - 1], 1);
        __syncthreads();
        if (t < 4) lbase[t] = (lcnt[t] > 0) ? atomicAdd(&dcnt[t], lcnt[t]) : 0;
        __syncthreads();
        if (d >= 1 && d <= 4) recs[(size_t)(d - 1) * N + lbase[d - 1] + p].x = v;
    }
}

// Blocks [0,SB): scan stage A. Rest: proj — h = x@pw+pb (f32 out + f16 shadow
// hh); t = h@mw1[0:128]+mb1.
__global__ __launch_bounds__(256) void k_mid(
        const int* __restrict__ degv, int* __restrict__ bsum, int SB,
        const float* __restrict__ x, const f16* __restrict__ pwp,
        const f16* __restrict__ mw1p, const float* __restrict__ pb,
        const float* __restrict__ mb1, float* __restrict__ h,
        f16* __restrict__ hh, f16* __restrict__ t, int N) {
    __shared__ __align__(16) f16 lds[4][16 * 136];
    __shared__ int wsum[4];
    int tid = threadIdx.x;
    if ((int)blockIdx.x < SB) {
        int idx = blockIdx.x * 256 + tid;
        int v = (idx < N) ? degv[idx] : 0;
#pragma unroll
        for (int off = 32; off; off >>= 1) v += __shfl_down(v, off, 64);
        if ((tid & 63) == 0) wsum[tid >> 6] = v;
        __syncthreads();
        if (tid == 0) bsum[blockIdx.x] = wsum[0] + wsum[1] + wsum[2] + wsum[3];
        return;
    }
    int lane = tid & 63, w = tid >> 6;
    int colx = lane & 15, quad = lane >> 4;
    int base = ((blockIdx.x - SB) * 4 + w) * 16;
    int arow = base + colx;
    int u = arow < N ? arow : N - 1;

    f32x4 c1[8];
#pragma unroll
    for (int nt = 0; nt < 8; nt++) c1[nt] = (f32x4){0.f, 0.f, 0.f, 0.f};
#pragma unroll
    for (int kt = 0; kt < 4; kt++) {
        f16x8 a = cvt8(x + (size_t)u * 128 + kt * 32 + quad * 8);
#pragma unroll
        for (int nt = 0; nt < 8; nt++) {
            f16x8 b = *(const f16x8*)(pwp + ((size_t)(kt * 8 + nt) * 64 + lane) * 8);
            c1[nt] = MFMA16(a, b, c1[nt]);
        }
    }
#pragma unroll
    for (int nt = 0; nt < 8; nt++) {
        float bias = pb[nt * 16 + colx];
#pragma unroll
        for (int reg = 0; reg < 4; reg++) {
            int row = quad * 4 + reg;
            int node = base + row;
            float v = c1[nt][reg] + bias;
            lds[w][row * 136 + nt * 16 + colx] = (f16)v;
            if (node < N) {
                h[(size_t)node * 128 + nt * 16 + colx] = v;
                hh[(size_t)node * 128 + nt * 16 + colx] = (f16)v;
            }
        }
    }
    f32x4 c2[8];
#pragma unroll
    for (int nt = 0; nt < 8; nt++) c2[nt] = (f32x4){0.f, 0.f, 0.f, 0.f};
#pragma unroll
    for (int kt = 0; kt < 4; kt++) {
        f16x8 a = *(const f16x8*)&lds[w][colx * 136 + kt * 32 + quad * 8];
#pragma unroll
        for (int nt = 0; nt < 8; nt++) {
            f16x8 b = *(const f16x8*)(mw1p + ((size_t)(kt * 8 + nt) * 64 + lane) * 8);
            c2[nt] = MFMA16(a, b, c2[nt]);
        }
    }
#pragma unroll
    for (int nt = 0; nt < 8; nt++) {
        float bias = mb1[nt * 16 + colx];
#pragma unroll
        for (int reg = 0; reg < 4; reg++) {
            int node = base + quad * 4 + reg;
            if (node < N) t[(size_t)node * 128 + nt * 16 + colx] = (f16)(c2[nt][reg] + bias);
        }
    }
}

__global__ __launch_bounds__(256) void k_scanC(const int* __restrict__ degv,
                                               const int* __restrict__ bsum,
                                               int* __restrict__ rowp, int N, int E) {
    __shared__ int lds[256];
    __shared__ int wo[4];
    int b = blockIdx.x, t = threadIdx.x;
    int idx = b * 256 + t;
    int v = (idx < N) ? degv[idx] : 0;
    lds[t] = v;
    __syncthreads();
#pragma unroll
    for (int d = 1; d < 256; d <<= 1) {
        int u = (t >= d) ? lds[t - d] : 0;
        __syncthreads();
        lds[t] += u;
        __syncthreads();
    }
    int off = 0;
    for (int j = t; j < b; j += 256) off += bsum[j];
#pragma unroll
    for (int o = 32; o; o >>= 1) off += __shfl_down(off, o, 64);
    if ((t & 63) == 0) wo[t >> 6] = off;
    __syncthreads();
    int boff = wo[0] + wo[1] + wo[2] + wo[3];
    if (idx < N) rowp[idx] = boff + lds[t] - v;
    if (b == 0 && t == 0) rowp[N] = E;
}

// Scatter edges into CSR. esea.x packs src | (dep[src] << 20) so the fused
// msg kernel can select tOrg vs tUpd per edge (N < 2^20, dep <= 4 fits).
__global__ __launch_bounds__(256) void k_scat(const int* __restrict__ ei,
                                              const float* __restrict__ eattr,
                                              const int* __restrict__ dep,
                                              const int* __restrict__ rowp,
                                              int* __restrict__ cur,
                                              int2* __restrict__ esea,
                                              int4* __restrict__ recs,
                                              const int* __restrict__ dcnt,
                                              int E, int N) {
    int gtid = blockIdx.x * 256 + threadIdx.x;
    int gsz = gridDim.x * 256;
    for (int e = gtid; e < E; e += gsz) {
        int s = ei[e], d = ei[E + e];
        int p = rowp[d] + atomicAdd(&cur[d], 1);
        esea[p] = (int2){s | (dep[s] << 20), __float_as_int(eattr[e])};
    }
    for (int d4 = 0; d4 < 4; d4++) {
        int cnt = dcnt[d4];
        for (int i = gtid; i < cnt; i += gsz) {
            int4* r = &recs[(size_t)d4 * N + i];
            int u = r->x;
            r->y = rowp[u];
            r->z = rowp[u + 1];
        }
    }
}

// FUSED per-depth kernel, v3b: whole-chunk mega-burst + cross-chunk pipeline.
// (v3 bugfix: each gather thread owns a 128-B half-row = 8 x f16x8; v3
// staged only 4 x f16x8, leaving half of every tbuf row uninitialized.)
//
// 512 threads gather ALL staged edges (<=16/node, 256 rows x 256 B = 64 KB
// tbuf) + hh tile in one burst of independent loads, with the NEXT chunk's
// esea records prefetched during the current chunk's compute (loop-carried
// erec). Steady state exposes ~1 latency per chunk instead of ~11 (v2).
// 1 block/CU (113 KB LDS), 8 waves. deg>16 overflow (~2% of nodes) falls
// back to the per-wave serial tile loop. recs staged per 64-node
// super-chunk. Masking: edge slots j>=deg carry stale LDS; MFMA M-rows are
// independent and accumulation masks (quad*4+reg < rem), so garbage never
// reaches an output. Update phase: wave w owns nt=w (one 16-col slab).
__global__ __launch_bounds__(512) void k_md(
        const f16* __restrict__ tOrg, f16* __restrict__ tUpd,
        const float* __restrict__ mw1, const float* __restrict__ mb2,
        const f16* __restrict__ mw2p, const int2* __restrict__ esea,
        const int4* __restrict__ recs, const int* __restrict__ dcnt,
        const f16* __restrict__ hh, const f16* __restrict__ uw1p,
        const f16* __restrict__ uw2p, const f16* __restrict__ mw1p,
        const float* __restrict__ ub1, const float* __restrict__ ub2,
        const float* __restrict__ mb1, float* __restrict__ h,
        int dIdx, int N) {
    __shared__ __align__(16) f16 bsm[128 * 128];    // staged mw2p (32 KB)
    __shared__ __align__(16) f16 tbuf[256 * 136];   // 256 edge rows (68 KB)
    __shared__ __align__(16) f16 hbuf[16 * 136];    // hh tile
    __shared__ __align__(16) f16 pool[16 * 136];    // agg, then c2-out
    __shared__ __align__(16) f16 sout[16 * 136];    // c1-out
    __shared__ int idsA[64], se0A[64], se1A[64];    // super-chunk recs

    const int tid = threadIdx.x;
    const int lane = tid & 63;
    const int w = tid >> 6;                // 0..7
    const int colx = lane & 15, quad = lane >> 4;
    const int cnt = dcnt[dIdx];

    // stage bsm
    {
        const f16x8* s8 = (const f16x8*)mw2p;
        f16x8* d8 = (f16x8*)bsm;
#pragma unroll
        for (int i = 0; i < 4; i++) d8[i * 512 + tid] = s8[i * 512 + tid];
    }

    // per-thread constants
    const float* w1r = mw1 + 128 * 128;
    f16x8 w1h[4];
#pragma unroll
    for (int kt = 0; kt < 4; kt++) {
        f32x4 q0 = *(const f32x4*)(w1r + kt * 32 + quad * 8);
        f32x4 q1 = *(const f32x4*)(w1r + kt * 32 + quad * 8 + 4);
        w1h[kt][0] = (f16)q0[0]; w1h[kt][1] = (f16)q0[1];
        w1h[kt][2] = (f16)q0[2]; w1h[kt][3] = (f16)q0[3];
        w1h[kt][4] = (f16)q1[0]; w1h[kt][5] = (f16)q1[1];
        w1h[kt][6] = (f16)q1[2]; w1h[kt][7] = (f16)q1[3];
    }
    float mb2v[8];
#pragma unroll
    for (int nt = 0; nt < 8; nt++) mb2v[nt] = mb2[nt * 16 + colx];

    // gather-task decomposition (512 threads over 256 rows x 2 halves)
    const int trow = tid & 255;     // chunk row: node*16 + edge slot
    const int thalf = tid >> 8;     // 0/1 -> 128-B half of the t row
    const int tnode = trow >> 4;    // node 0..15 within chunk
    const int tj = trow & 15;       // edge slot 0..15

    const int b = blockIdx.x, nb = gridDim.x;
    const int s0 = (int)((long long)cnt * b / nb);
    const int s1 = (int)((long long)cnt * (b + 1) / nb);

    auto srow = [&](int sv) -> const f16* {
        const f16* tb = ((unsigned)((sv >> 20) - 1) < (unsigned)dIdx) ? tUpd : tOrg;
        return tb + (size_t)(sv & 0xFFFFF) * 128;
    };

    for (int ss = s0; ss < s1; ss += 64) {
        int scc = s1 - ss; if (scc > 64) scc = 64;
        __syncthreads();  // all reads of idsA/se*/tbuf from prior chunks done
        if (tid < 64) {
            if (tid < scc) {
                int4 r = recs[(size_t)dIdx * N + ss + tid];
                idsA[tid] = r.x; se0A[tid] = r.y; se1A[tid] = r.z;
            } else {
                idsA[tid] = 0; se0A[tid] = 0; se1A[tid] = 0;
            }
        }
        __syncthreads();
        int nch = (scc + 15) >> 4;

        // prefetch first chunk's edge record
        int2 erec = (int2){0, 0};
        {
            int d0 = se1A[tnode] - se0A[tnode];
            if (tj < d0) erec = esea[se0A[tnode] + tj];
        }

        for (int ci = 0; ci < nch; ci++) {
            int cc = scc - ci * 16; if (cc > 16) cc = 16;
            int gidx = ci * 16 + tnode;
            int deg = se1A[gidx] - se0A[gidx];
            bool tval = (tj < deg);
            // ---- issue t-row burst: full 128-B half = 8 independent 16-B loads
            f16x8 tld[8];
            if (tval) {
                const f16* tr = srow(erec.x) + thalf * 64;
#pragma unroll
                for (int i = 0; i < 8; i++) tld[i] = *(const f16x8*)(tr + i * 8);
            }
            // ---- issue hh burst
            f16x8 hld;
            if (tid < 256) {
                int hrow = tid >> 4, hseg = tid & 15;
                hld = *(const f16x8*)(hh + (size_t)idsA[ci * 16 + hrow] * 128 + hseg * 8);
            }
            // ---- prefetch next chunk's edge record (in flight across compute)
            int2 erecN = (int2){0, 0};
            if (ci + 1 < nch) {
                int g2 = (ci + 1) * 16 + tnode;
                int d2 = se1A[g2] - se0A[g2];
                if (tj < d2) erecN = esea[se0A[g2] + tj];
            }
            // ---- commit bursts to LDS
            if (tval) {
                f16* dst = &tbuf[trow * 136 + thalf * 64];
#pragma unroll
                for (int i = 0; i < 8; i++) *(f16x8*)(dst + i * 8) = tld[i];
                if (thalf == 0) tbuf[trow * 136 + 128] = (f16)__int_as_float(erec.y);
            }
            if (tid < 256) {
                int hrow = tid >> 4, hseg = tid & 15;
                *(f16x8*)&hbuf[hrow * 136 + hseg * 8] = hld;
            }
            __syncthreads();

            // ---- msg compute: wave w handles nodes 2w, 2w+1
#pragma unroll
            for (int nn = 0; nn < 2; nn++) {
                int n = 2 * w + nn;
                int gi = ci * 16 + n;
                int nd = se1A[gi] - se0A[gi];
                float aggv[8] = {0.f, 0.f, 0.f, 0.f, 0.f, 0.f, 0.f, 0.f};
                if (nd > 0) {
                    // staged tile from tbuf
                    f16 eah = tbuf[(n * 16 + colx) * 136 + 128];
                    f16x8 afr[4];
#pragma unroll
                    for (int kt = 0; kt < 4; kt++) {
                        f16x8 v = *(const f16x8*)&tbuf[(n * 16 + colx) * 136 + kt * 32 + quad * 8];
                        f16x8 o;
#pragma unroll
                        for (int j2 = 0; j2 < 8; j2++) {
                            f16 qv = v[j2] + eah * w1h[kt][j2];
                            o[j2] = qv > (f16)0 ? qv : (f16)0;
                        }
                        afr[kt] = o;
                    }
                    int rem0 = nd < 16 ? nd : 16;
#pragma unroll
                    for (int nt = 0; nt < 8; nt++) {
                        f32x4 c = (f32x4){0.f, 0.f, 0.f, 0.f};
#pragma unroll
                        for (int kt = 0; kt < 4; kt++) {
                            f16x8 bb = *(const f16x8*)&bsm[((kt * 8 + nt) * 64 + lane) * 8];
                            c = MFMA16(afr[kt], bb, c);
                        }
#pragma unroll
                        for (int reg = 0; reg < 4; reg++)
                            if (quad * 4 + reg < rem0)
                                aggv[nt] += fmaxf(c[reg] + mb2v[nt], 0.f);
                    }
                    // overflow tiles (deg > 16): per-wave serial, direct loads
                    for (int bs = 16; bs < nd; bs += 16) {
                        int lim = se1A[gi] - 1;
                        int es = se0A[gi] + bs + colx; if (es > lim) es = lim;
                        int2 er = esea[es];
                        f16 eah2 = (f16)__int_as_float(er.y);
                        const f16* trw = srow(er.x);
                        f16x8 af2[4];
#pragma unroll
                        for (int kt = 0; kt < 4; kt++) {
                            f16x8 v = *(const f16x8*)(trw + kt * 32 + quad * 8);
                            f16x8 o;
#pragma unroll
                            for (int j2 = 0; j2 < 8; j2++) {
                                f16 qv = v[j2] + eah2 * w1h[kt][j2];
                                o[j2] = qv > (f16)0 ? qv : (f16)0;
                            }
                            af2[kt] = o;
                        }
                        int rem = nd - bs;
#pragma unroll
                        for (int nt = 0; nt < 8; nt++) {
                            f32x4 c = (f32x4){0.f, 0.f, 0.f, 0.f};
#pragma unroll
                            for (int kt = 0; kt < 4; kt++) {
                                f16x8 bb = *(const f16x8*)&bsm[((kt * 8 + nt) * 64 + lane) * 8];
                                c = MFMA16(af2[kt], bb, c);
                            }
#pragma unroll
                            for (int reg = 0; reg < 4; reg++)
                                if (quad * 4 + reg < rem)
                                    aggv[nt] += fmaxf(c[reg] + mb2v[nt], 0.f);
                        }
                    }
                }
                float inv = 1.f / (float)(nd > 1 ? nd : 1);
#pragma unroll
                for (int nt = 0; nt < 8; nt++) {
                    float s = aggv[nt];
                    s += __shfl_xor(s, 16, 64);
                    s += __shfl_xor(s, 32, 64);
                    if (quad == 0) pool[n * 136 + nt * 16 + colx] = (f16)(s * inv);
                }
            }
            __syncthreads();

            // ---- update phase: wave w owns nt = w.
            // c1: upd_in = [hbuf | pool], K=256
            f32x4 c1 = (f32x4){0.f, 0.f, 0.f, 0.f};
#pragma unroll
            for (int kt = 0; kt < 8; kt++) {
                f16x8 a;
                if (kt < 4)
                    a = *(const f16x8*)&hbuf[colx * 136 + kt * 32 + quad * 8];
                else
                    a = *(const f16x8*)&pool[colx * 136 + (kt - 4) * 32 + quad * 8];
                f16x8 bb = *(const f16x8*)(uw1p + ((size_t)(kt * 8 + w) * 64 + lane) * 8);
                c1 = MFMA16(a, bb, c1);
            }
            {
                float bias = ub1[w * 16 + colx];
#pragma unroll
                for (int reg = 0; reg < 4; reg++) {
                    int row = quad * 4 + reg;
                    sout[row * 136 + w * 16 + colx] = (f16)fmaxf(c1[reg] + bias, 0.f);
                }
            }
            __syncthreads();
            // c2: h_new = relu(sout @ uw2 + ub2) -> pool + global h
            f32x4 c2 = (f32x4){0.f, 0.f, 0.f, 0.f};
#pragma unroll
            for (int kt = 0; kt < 4; kt++) {
                f16x8 a = *(const f16x8*)&sout[colx * 136 + kt * 32 + quad * 8];
                f16x8 bb = *(const f16x8*)(uw2p + ((size_t)(kt * 8 + w) * 64 + lane) * 8);
                c2 = MFMA16(a, bb, c2);
            }
            {
                float bias = ub2[w * 16 + colx];
#pragma unroll
                for (int reg = 0; reg < 4; reg++) {
                    int row = quad * 4 + reg;
                    float v = fmaxf(c2[reg] + bias, 0.f);
                    pool[row * 136 + w * 16 + colx] = (f16)v;
                    if (row < cc)
                        h[(size_t)idsA[ci * 16 + row] * 128 + w * 16 + colx] = v;
                }
            }
            __syncthreads();
            // c3: t recompute for later depths
            if (dIdx < 3) {
                f32x4 c3 = (f32x4){0.f, 0.f, 0.f, 0.f};
#pragma unroll
                for (int kt = 0; kt < 4; kt++) {
                    f16x8 a = *(const f16x8*)&pool[colx * 136 + kt * 32 + quad * 8];
                    f16x8 bb = *(const f16x8*)(mw1p + ((size_t)(kt * 8 + w) * 64 + lane) * 8);
                    c3 = MFMA16(a, bb, c3);
                }
                float bias = mb1[w * 16 + colx];
#pragma unroll
                for (int reg = 0; reg < 4; reg++) {
                    int row = quad * 4 + reg;
                    if (row < cc)
                        tUpd[(size_t)idsA[ci * 16 + row] * 128 + w * 16 + colx] =
                            (f16)(c3[reg] + bias);
                }
            }
            __syncthreads();  // tbuf/hbuf/pool/sout reusable
            erec = erecN;
        }
    }
}

extern "C" void kernel_launch(void* const* d_in, const int* in_sizes, int n_in,
                              void* d_out, int out_size, void* d_ws, size_t ws_size,
                              hipStream_t stream) {
    const float* x    = (const float*)d_in[0];
    const int*   ei   = (const int*)d_in[1];
    const float* eatt = (const float*)d_in[2];
    const int*   dep  = (const int*)d_in[3];
    const float* pw   = (const float*)d_in[4];
    const float* pb   = (const float*)d_in[5];
    const float* mw1  = (const float*)d_in[6];
    const float* mb1  = (const float*)d_in[7];
    const float* mw2  = (const float*)d_in[8];
    const float* mb2  = (const float*)d_in[9];
    const float* uw1  = (const float*)d_in[10];
    const float* ub1  = (const float*)d_in[11];
    const float* uw2  = (const float*)d_in[12];
    const float* ub2  = (const float*)d_in[13];
    float* h = (float*)d_out;

    int N = in_sizes[3];
    int E = in_sizes[1] / 2;
    int NB = (N + 255) / 256;
    int CB = (E + 255) / 256;

    char* ws = (char*)d_ws;
    size_t o = 0;
    auto alloc = [&](size_t bytes) -> char* {
        char* p = ws + o;
        o += (bytes + 255) & ~(size_t)255;
        return p;
    };
    f16*   t    = (f16*)alloc((size_t)N * 128 * 2);   // tOrg
    f16*   hh   = (f16*)alloc((size_t)N * 128 * 2);
    f16*   tUpd = (f16*)alloc((size_t)N * 128 * 2);
    char*  z0   = (char*)alloc(0);
    int*   degv = (int*)alloc((size_t)N * 4);
    int*   cur  = (int*)alloc((size_t)N * 4);
    int*   dcnt = (int*)alloc(64);
    size_t zbytes = (size_t)((char*)alloc(0) - z0);
    int*   rowp = (int*)alloc((size_t)(N + 1) * 4);
    int*   bsum = (int*)alloc((size_t)NB * 4);
    int2*  esea = (int2*)alloc((size_t)E * 8);
    int4*  recs = (int4*)alloc((size_t)4 * N * 16);
    f16*   pwp  = (f16*)alloc(128 * 128 * 2);
    f16*   mw1p = (f16*)alloc(128 * 128 * 2);
    f16*   mw2p = (f16*)alloc(128 * 128 * 2);
    f16*   uw1p = (f16*)alloc(256 * 128 * 2);
    f16*   uw2p = (f16*)alloc(128 * 128 * 2);

    hipMemsetAsync(z0, 0, zbytes, stream);

    k_prep<<<48 + CB + NB, 256, 0, stream>>>(pw, mw1, mw2, uw1, uw2,
                                             pwp, mw1p, mw2p, uw1p, uw2p,
                                             ei, degv, dep, dcnt, recs, CB, E, N);
    int PB = (N + 63) / 64;
    k_mid<<<NB + PB, 256, 0, stream>>>(degv, bsum, NB, x, pwp, mw1p, pb, mb1,
                                       h, hh, t, N);
    k_scanC<<<NB, 256, 0, stream>>>(degv, bsum, rowp, N, E);
    k_scat<<<CB, 256, 0, stream>>>(ei, eatt, dep, rowp, cur, esea, recs, dcnt, E, N);

    for (int d = 0; d < 4; d++) {
        k_md<<<256, 512, 0, stream>>>(t, tUpd, mw1, mb2, mw2p, esea, recs, dcnt,
                                      hh, uw1p, uw2p, mw1p, ub1, ub2, mb1, h,
                                      d, N);
    }
}

// Round 5
// 467.838 us; speedup vs baseline: 1.0047x; 1.0047x over previous
//
#include <hip/hip_runtime.h>

typedef _Float16 f16;
typedef f16 f16x2 __attribute__((ext_vector_type(2)));
typedef f16 f16x8 __attribute__((ext_vector_type(8)));
typedef float f32x4 __attribute__((ext_vector_type(4)));
typedef float f32x2 __attribute__((ext_vector_type(2)));

#define MFMA16(a, b, c) __builtin_amdgcn_mfma_f32_16x16x32_f16((a), (b), (c), 0, 0, 0)

static __device__ __forceinline__ f16x8 cvt8(const float* __restrict__ p) {
    f32x4 p0 = *(const f32x4*)p;
    f32x4 p1 = *(const f32x4*)(p + 4);
    f16x8 a;
    a[0] = (f16)p0[0]; a[1] = (f16)p0[1]; a[2] = (f16)p0[2]; a[3] = (f16)p0[3];
    a[4] = (f16)p1[0]; a[5] = (f16)p1[1]; a[6] = (f16)p1[2]; a[7] = (f16)p1[3];
    return a;
}

// Fused prep: blocks [0,48) repack weights to B-fragment order; [48,48+CB)
// count in-degrees; rest classify nodes by depth into recs[].x.
__global__ __launch_bounds__(256) void k_prep(
        const float* __restrict__ pw, const float* __restrict__ mw1,
        const float* __restrict__ mw2, const float* __restrict__ uw1,
        const float* __restrict__ uw2,
        f16* __restrict__ pwp, f16* __restrict__ mw1p, f16* __restrict__ mw2p,
        f16* __restrict__ uw1p, f16* __restrict__ uw2p,
        const int* __restrict__ ei, int* __restrict__ degv,
        const int* __restrict__ dep, int* __restrict__ dcnt,
        int4* __restrict__ recs, int CB, int E, int N) {
    __shared__ int lcnt[4];
    __shared__ int lbase[4];
    int b = blockIdx.x;
    int t = threadIdx.x;
    if (b < 48) {
        const float* W; f16* out; int fb;
        if (b < 8)       { W = pw;  out = pwp;  fb = b; }
        else if (b < 16) { W = mw1; out = mw1p; fb = b - 8; }
        else if (b < 24) { W = mw2; out = mw2p; fb = b - 16; }
        else if (b < 40) { W = uw1; out = uw1p; fb = b - 24; }
        else             { W = uw2; out = uw2p; fb = b - 40; }
        int idx = fb * 256 + t;
        int lane = idx & 63;
        int nt = (idx >> 6) & 7;
        int kt = idx >> 9;
        int colx = lane & 15, quad = lane >> 4;
        f16* o = out + (size_t)idx * 8;
        const float* wb = W + (size_t)(kt * 32 + quad * 8) * 128 + nt * 16 + colx;
#pragma unroll
        for (int j = 0; j < 8; j++) o[j] = (f16)wb[(size_t)j * 128];
    } else if (b < 48 + CB) {
        int e = (b - 48) * 256 + t;
        if (e < E) atomicAdd(&degv[ei[E + e]], 1);
    } else {
        if (t < 4) lcnt[t] = 0;
        __syncthreads();
        int v = (b - 48 - CB) * 256 + t;
        int d = (v < N) ? dep[v] : 0;
        int p = -1;
        if (d >= 1 && d <= 4) p = atomicAdd(&lcnt[d - 1], 1);
        __syncthreads();
        if (t < 4) lbase[t] = (lcnt[t] > 0) ? atomicAdd(&dcnt[t], lcnt[t]) : 0;
        __syncthreads();
        if (d >= 1 && d <= 4) recs[(size_t)(d - 1) * N + lbase[d - 1] + p].x = v;
    }
}

// Blocks [0,SB): scan stage A. Rest: proj — h = x@pw+pb (f32 out + f16 shadow
// hh); t = h@mw1[0:128]+mb1.
__global__ __launch_bounds__(256) void k_mid(
        const int* __restrict__ degv, int* __restrict__ bsum, int SB,
        const float* __restrict__ x, const f16* __restrict__ pwp,
        const f16* __restrict__ mw1p, const float* __restrict__ pb,
        const float* __restrict__ mb1, float* __restrict__ h,
        f16* __restrict__ hh, f16* __restrict__ t, int N) {
    __shared__ __align__(16) f16 lds[4][16 * 136];
    __shared__ int wsum[4];
    int tid = threadIdx.x;
    if ((int)blockIdx.x < SB) {
        int idx = blockIdx.x * 256 + tid;
        int v = (idx < N) ? degv[idx] : 0;
#pragma unroll
        for (int off = 32; off; off >>= 1) v += __shfl_down(v, off, 64);
        if ((tid & 63) == 0) wsum[tid >> 6] = v;
        __syncthreads();
        if (tid == 0) bsum[blockIdx.x] = wsum[0] + wsum[1] + wsum[2] + wsum[3];
        return;
    }
    int lane = tid & 63, w = tid >> 6;
    int colx = lane & 15, quad = lane >> 4;
    int base = ((blockIdx.x - SB) * 4 + w) * 16;
    int arow = base + colx;
    int u = arow < N ? arow : N - 1;

    f32x4 c1[8];
#pragma unroll
    for (int nt = 0; nt < 8; nt++) c1[nt] = (f32x4){0.f, 0.f, 0.f, 0.f};
#pragma unroll
    for (int kt = 0; kt < 4; kt++) {
        f16x8 a = cvt8(x + (size_t)u * 128 + kt * 32 + quad * 8);
#pragma unroll
        for (int nt = 0; nt < 8; nt++) {
            f16x8 b = *(const f16x8*)(pwp + ((size_t)(kt * 8 + nt) * 64 + lane) * 8);
            c1[nt] = MFMA16(a, b, c1[nt]);
        }
    }
#pragma unroll
    for (int nt = 0; nt < 8; nt++) {
        float bias = pb[nt * 16 + colx];
#pragma unroll
        for (int reg = 0; reg < 4; reg++) {
            int row = quad * 4 + reg;
            int node = base + row;
            float v = c1[nt][reg] + bias;
            lds[w][row * 136 + nt * 16 + colx] = (f16)v;
            if (node < N) {
                h[(size_t)node * 128 + nt * 16 + colx] = v;
                hh[(size_t)node * 128 + nt * 16 + colx] = (f16)v;
            }
        }
    }
    f32x4 c2[8];
#pragma unroll
    for (int nt = 0; nt < 8; nt++) c2[nt] = (f32x4){0.f, 0.f, 0.f, 0.f};
#pragma unroll
    for (int kt = 0; kt < 4; kt++) {
        f16x8 a = *(const f16x8*)&lds[w][colx * 136 + kt * 32 + quad * 8];
#pragma unroll
        for (int nt = 0; nt < 8; nt++) {
            f16x8 b = *(const f16x8*)(mw1p + ((size_t)(kt * 8 + nt) * 64 + lane) * 8);
            c2[nt] = MFMA16(a, b, c2[nt]);
        }
    }
#pragma unroll
    for (int nt = 0; nt < 8; nt++) {
        float bias = mb1[nt * 16 + colx];
#pragma unroll
        for (int reg = 0; reg < 4; reg++) {
            int node = base + quad * 4 + reg;
            if (node < N) t[(size_t)node * 128 + nt * 16 + colx] = (f16)(c2[nt][reg] + bias);
        }
    }
}

__global__ __launch_bounds__(256) void k_scanC(const int* __restrict__ degv,
                                               const int* __restrict__ bsum,
                                               int* __restrict__ rowp, int N, int E) {
    __shared__ int lds[256];
    __shared__ int wo[4];
    int b = blockIdx.x, t = threadIdx.x;
    int idx = b * 256 + t;
    int v = (idx < N) ? degv[idx] : 0;
    lds[t] = v;
    __syncthreads();
#pragma unroll
    for (int d = 1; d < 256; d <<= 1) {
        int u = (t >= d) ? lds[t - d] : 0;
        __syncthreads();
        lds[t] += u;
        __syncthreads();
    }
    int off = 0;
    for (int j = t; j < b; j += 256) off += bsum[j];
#pragma unroll
    for (int o = 32; o; o >>= 1) off += __shfl_down(off, o, 64);
    if ((t & 63) == 0) wo[t >> 6] = off;
    __syncthreads();
    int boff = wo[0] + wo[1] + wo[2] + wo[3];
    if (idx < N) rowp[idx] = boff + lds[t] - v;
    if (b == 0 && t == 0) rowp[N] = E;
}

// Scatter edges into CSR. esea.x packs src | (dep[src] << 20) so the fused
// msg kernel can select tOrg vs tUpd per edge (N < 2^20, dep <= 4 fits).
__global__ __launch_bounds__(256) void k_scat(const int* __restrict__ ei,
                                              const float* __restrict__ eattr,
                                              const int* __restrict__ dep,
                                              const int* __restrict__ rowp,
                                              int* __restrict__ cur,
                                              int2* __restrict__ esea,
                                              int4* __restrict__ recs,
                                              const int* __restrict__ dcnt,
                                              int E, int N) {
    int gtid = blockIdx.x * 256 + threadIdx.x;
    int gsz = gridDim.x * 256;
    for (int e = gtid; e < E; e += gsz) {
        int s = ei[e], d = ei[E + e];
        int p = rowp[d] + atomicAdd(&cur[d], 1);
        esea[p] = (int2){s | (dep[s] << 20), __float_as_int(eattr[e])};
    }
    for (int d4 = 0; d4 < 4; d4++) {
        int cnt = dcnt[d4];
        for (int i = gtid; i < cnt; i += gsz) {
            int4* r = &recs[(size_t)d4 * N + i];
            int u = r->x;
            r->y = rowp[u];
            r->z = rowp[u + 1];
        }
    }
}

// FUSED per-depth kernel, v4: v3b + __launch_bounds__(512, 2).
//
// v3b's counters showed 183 MB HBM traffic/dispatch (vs 22 MB of real
// data): the compiler's default 512-thread budget of 128 VGPRs
// (VGPR_Count=128) forced the mega-burst registers (tld[8]=32 VGPRs +
// hld + erec/erecN) to spill to scratch — ~50 MB written + re-read per
// dispatch, plus a 178-us first dispatch for scratch allocation. LDS is
// 113 KB -> 1 block/CU regardless, so capping at 128 VGPRs bought
// nothing. (512, 2) = 2 waves/EU grants the full 256-VGPR budget; the
// burst stays in registers.
//
// Structure (unchanged from v3b): 512 threads gather ALL staged edges
// (<=16/node, 256 rows x 256 B = 64 KB tbuf) + hh tile in one burst of
// independent loads, next chunk's esea records prefetched during compute
// (loop-carried erec). deg>16 overflow (~2% of nodes) falls back to the
// per-wave serial tile loop. Masking: edge slots j>=deg carry stale LDS;
// MFMA M-rows are independent and accumulation masks (quad*4+reg < rem).
// Update phase: wave w owns nt=w (one 16-col slab).
__global__ __launch_bounds__(512, 2) void k_md(
        const f16* __restrict__ tOrg, f16* __restrict__ tUpd,
        const float* __restrict__ mw1, const float* __restrict__ mb2,
        const f16* __restrict__ mw2p, const int2* __restrict__ esea,
        const int4* __restrict__ recs, const int* __restrict__ dcnt,
        const f16* __restrict__ hh, const f16* __restrict__ uw1p,
        const f16* __restrict__ uw2p, const f16* __restrict__ mw1p,
        const float* __restrict__ ub1, const float* __restrict__ ub2,
        const float* __restrict__ mb1, float* __restrict__ h,
        int dIdx, int N) {
    __shared__ __align__(16) f16 bsm[128 * 128];    // staged mw2p (32 KB)
    __shared__ __align__(16) f16 tbuf[256 * 136];   // 256 edge rows (68 KB)
    __shared__ __align__(16) f16 hbuf[16 * 136];    // hh tile
    __shared__ __align__(16) f16 pool[16 * 136];    // agg, then c2-out
    __shared__ __align__(16) f16 sout[16 * 136];    // c1-out
    __shared__ int idsA[64], se0A[64], se1A[64];    // super-chunk recs

    const int tid = threadIdx.x;
    const int lane = tid & 63;
    const int w = tid >> 6;                // 0..7
    const int colx = lane & 15, quad = lane >> 4;
    const int cnt = dcnt[dIdx];

    // stage bsm
    {
        const f16x8* s8 = (const f16x8*)mw2p;
        f16x8* d8 = (f16x8*)bsm;
#pragma unroll
        for (int i = 0; i < 4; i++) d8[i * 512 + tid] = s8[i * 512 + tid];
    }

    // per-thread constants
    const float* w1r = mw1 + 128 * 128;
    f16x8 w1h[4];
#pragma unroll
    for (int kt = 0; kt < 4; kt++) {
        f32x4 q0 = *(const f32x4*)(w1r + kt * 32 + quad * 8);
        f32x4 q1 = *(const f32x4*)(w1r + kt * 32 + quad * 8 + 4);
        w1h[kt][0] = (f16)q0[0]; w1h[kt][1] = (f16)q0[1];
        w1h[kt][2] = (f16)q0[2]; w1h[kt][3] = (f16)q0[3];
        w1h[kt][4] = (f16)q1[0]; w1h[kt][5] = (f16)q1[1];
        w1h[kt][6] = (f16)q1[2]; w1h[kt][7] = (f16)q1[3];
    }
    float mb2v[8];
#pragma unroll
    for (int nt = 0; nt < 8; nt++) mb2v[nt] = mb2[nt * 16 + colx];

    // gather-task decomposition (512 threads over 256 rows x 2 halves)
    const int trow = tid & 255;     // chunk row: node*16 + edge slot
    const int thalf = tid >> 8;     // 0/1 -> 128-B half of the t row
    const int tnode = trow >> 4;    // node 0..15 within chunk
    const int tj = trow & 15;       // edge slot 0..15

    const int b = blockIdx.x, nb = gridDim.x;
    const int s0 = (int)((long long)cnt * b / nb);
    const int s1 = (int)((long long)cnt * (b + 1) / nb);

    auto srow = [&](int sv) -> const f16* {
        const f16* tb = ((unsigned)((sv >> 20) - 1) < (unsigned)dIdx) ? tUpd : tOrg;
        return tb + (size_t)(sv & 0xFFFFF) * 128;
    };

    for (int ss = s0; ss < s1; ss += 64) {
        int scc = s1 - ss; if (scc > 64) scc = 64;
        __syncthreads();  // all reads of idsA/se*/tbuf from prior chunks done
        if (tid < 64) {
            if (tid < scc) {
                int4 r = recs[(size_t)dIdx * N + ss + tid];
                idsA[tid] = r.x; se0A[tid] = r.y; se1A[tid] = r.z;
            } else {
                idsA[tid] = 0; se0A[tid] = 0; se1A[tid] = 0;
            }
        }
        __syncthreads();
        int nch = (scc + 15) >> 4;

        // prefetch first chunk's edge record
        int2 erec = (int2){0, 0};
        {
            int d0 = se1A[tnode] - se0A[tnode];
            if (tj < d0) erec = esea[se0A[tnode] + tj];
        }

        for (int ci = 0; ci < nch; ci++) {
            int cc = scc - ci * 16; if (cc > 16) cc = 16;
            int gidx = ci * 16 + tnode;
            int deg = se1A[gidx] - se0A[gidx];
            bool tval = (tj < deg);
            // ---- issue t-row burst: full 128-B half = 8 independent 16-B loads
            f16x8 tld[8];
            if (tval) {
                const f16* tr = srow(erec.x) + thalf * 64;
#pragma unroll
                for (int i = 0; i < 8; i++) tld[i] = *(const f16x8*)(tr + i * 8);
            }
            // ---- issue hh burst
            f16x8 hld;
            if (tid < 256) {
                int hrow = tid >> 4, hseg = tid & 15;
                hld = *(const f16x8*)(hh + (size_t)idsA[ci * 16 + hrow] * 128 + hseg * 8);
            }
            // ---- prefetch next chunk's edge record (in flight across compute)
            int2 erecN = (int2){0, 0};
            if (ci + 1 < nch) {
                int g2 = (ci + 1) * 16 + tnode;
                int d2 = se1A[g2] - se0A[g2];
                if (tj < d2) erecN = esea[se0A[g2] + tj];
            }
            // ---- commit bursts to LDS
            if (tval) {
                f16* dst = &tbuf[trow * 136 + thalf * 64];
#pragma unroll
                for (int i = 0; i < 8; i++) *(f16x8*)(dst + i * 8) = tld[i];
                if (thalf == 0) tbuf[trow * 136 + 128] = (f16)__int_as_float(erec.y);
            }
            if (tid < 256) {
                int hrow = tid >> 4, hseg = tid & 15;
                *(f16x8*)&hbuf[hrow * 136 + hseg * 8] = hld;
            }
            __syncthreads();

            // ---- msg compute: wave w handles nodes 2w, 2w+1
#pragma unroll
            for (int nn = 0; nn < 2; nn++) {
                int n = 2 * w + nn;
                int gi = ci * 16 + n;
                int nd = se1A[gi] - se0A[gi];
                float aggv[8] = {0.f, 0.f, 0.f, 0.f, 0.f, 0.f, 0.f, 0.f};
                if (nd > 0) {
                    // staged tile from tbuf
                    f16 eah = tbuf[(n * 16 + colx) * 136 + 128];
                    f16x8 afr[4];
#pragma unroll
                    for (int kt = 0; kt < 4; kt++) {
                        f16x8 v = *(const f16x8*)&tbuf[(n * 16 + colx) * 136 + kt * 32 + quad * 8];
                        f16x8 o;
#pragma unroll
                        for (int j2 = 0; j2 < 8; j2++) {
                            f16 qv = v[j2] + eah * w1h[kt][j2];
                            o[j2] = qv > (f16)0 ? qv : (f16)0;
                        }
                        afr[kt] = o;
                    }
                    int rem0 = nd < 16 ? nd : 16;
#pragma unroll
                    for (int nt = 0; nt < 8; nt++) {
                        f32x4 c = (f32x4){0.f, 0.f, 0.f, 0.f};
#pragma unroll
                        for (int kt = 0; kt < 4; kt++) {
                            f16x8 bb = *(const f16x8*)&bsm[((kt * 8 + nt) * 64 + lane) * 8];
                            c = MFMA16(afr[kt], bb, c);
                        }
#pragma unroll
                        for (int reg = 0; reg < 4; reg++)
                            if (quad * 4 + reg < rem0)
                                aggv[nt] += fmaxf(c[reg] + mb2v[nt], 0.f);
                    }
                    // overflow tiles (deg > 16): per-wave serial, direct loads
                    for (int bs = 16; bs < nd; bs += 16) {
                        int lim = se1A[gi] - 1;
                        int es = se0A[gi] + bs + colx; if (es > lim) es = lim;
                        int2 er = esea[es];
                        f16 eah2 = (f16)__int_as_float(er.y);
                        const f16* trw = srow(er.x);
                        f16x8 af2[4];
#pragma unroll
                        for (int kt = 0; kt < 4; kt++) {
                            f16x8 v = *(const f16x8*)(trw + kt * 32 + quad * 8);
                            f16x8 o;
#pragma unroll
                            for (int j2 = 0; j2 < 8; j2++) {
                                f16 qv = v[j2] + eah2 * w1h[kt][j2];
                                o[j2] = qv > (f16)0 ? qv : (f16)0;
                            }
                            af2[kt] = o;
                        }
                        int rem = nd - bs;
#pragma unroll
                        for (int nt = 0; nt < 8; nt++) {
                            f32x4 c = (f32x4){0.f, 0.f, 0.f, 0.f};
#pragma unroll
                            for (int kt = 0; kt < 4; kt++) {
                                f16x8 bb = *(const f16x8*)&bsm[((kt * 8 + nt) * 64 + lane) * 8];
                                c = MFMA16(af2[kt], bb, c);
                            }
#pragma unroll
                            for (int reg = 0; reg < 4; reg++)
                                if (quad * 4 + reg < rem)
                                    aggv[nt] += fmaxf(c[reg] + mb2v[nt], 0.f);
                        }
                    }
                }
                float inv = 1.f / (float)(nd > 1 ? nd : 1);
#pragma unroll
                for (int nt = 0; nt < 8; nt++) {
                    float s = aggv[nt];
                    s += __shfl_xor(s, 16, 64);
                    s += __shfl_xor(s, 32, 64);
                    if (quad == 0) pool[n * 136 + nt * 16 + colx] = (f16)(s * inv);
                }
            }
            __syncthreads();

            // ---- update phase: wave w owns nt = w.
            // c1: upd_in = [hbuf | pool], K=256
            f32x4 c1 = (f32x4){0.f, 0.f, 0.f, 0.f};
#pragma unroll
            for (int kt = 0; kt < 8; kt++) {
                f16x8 a;
                if (kt < 4)
                    a = *(const f16x8*)&hbuf[colx * 136 + kt * 32 + quad * 8];
                else
                    a = *(const f16x8*)&pool[colx * 136 + (kt - 4) * 32 + quad * 8];
                f16x8 bb = *(const f16x8*)(uw1p + ((size_t)(kt * 8 + w) * 64 + lane) * 8);
                c1 = MFMA16(a, bb, c1);
            }
            {
                float bias = ub1[w * 16 + colx];
#pragma unroll
                for (int reg = 0; reg < 4; reg++) {
                    int row = quad * 4 + reg;
                    sout[row * 136 + w * 16 + colx] = (f16)fmaxf(c1[reg] + bias, 0.f);
                }
            }
            __syncthreads();
            // c2: h_new = relu(sout @ uw2 + ub2) -> pool + global h
            f32x4 c2 = (f32x4){0.f, 0.f, 0.f, 0.f};
#pragma unroll
            for (int kt = 0; kt < 4; kt++) {
                f16x8 a = *(const f16x8*)&sout[colx * 136 + kt * 32 + quad * 8];
                f16x8 bb = *(const f16x8*)(uw2p + ((size_t)(kt * 8 + w) * 64 + lane) * 8);
                c2 = MFMA16(a, bb, c2);
            }
            {
                float bias = ub2[w * 16 + colx];
#pragma unroll
                for (int reg = 0; reg < 4; reg++) {
                    int row = quad * 4 + reg;
                    float v = fmaxf(c2[reg] + bias, 0.f);
                    pool[row * 136 + w * 16 + colx] = (f16)v;
                    if (row < cc)
                        h[(size_t)idsA[ci * 16 + row] * 128 + w * 16 + colx] = v;
                }
            }
            __syncthreads();
            // c3: t recompute for later depths
            if (dIdx < 3) {
                f32x4 c3 = (f32x4){0.f, 0.f, 0.f, 0.f};
#pragma unroll
                for (int kt = 0; kt < 4; kt++) {
                    f16x8 a = *(const f16x8*)&pool[colx * 136 + kt * 32 + quad * 8];
                    f16x8 bb = *(const f16x8*)(mw1p + ((size_t)(kt * 8 + w) * 64 + lane) * 8);
                    c3 = MFMA16(a, bb, c3);
                }
                float bias = mb1[w * 16 + colx];
#pragma unroll
                for (int reg = 0; reg < 4; reg++) {
                    int row = quad * 4 + reg;
                    if (row < cc)
                        tUpd[(size_t)idsA[ci * 16 + row] * 128 + w * 16 + colx] =
                            (f16)(c3[reg] + bias);
                }
            }
            __syncthreads();  // tbuf/hbuf/pool/sout reusable
            erec = erecN;
        }
    }
}

extern "C" void kernel_launch(void* const* d_in, const int* in_sizes, int n_in,
                              void* d_out, int out_size, void* d_ws, size_t ws_size,
                              hipStream_t stream) {
    const float* x    = (const float*)d_in[0];
    const int*   ei   = (const int*)d_in[1];
    const float* eatt = (const float*)d_in[2];
    const int*   dep  = (const int*)d_in[3];
    const float* pw   = (const float*)d_in[4];
    const float* pb   = (const float*)d_in[5];
    const float* mw1  = (const float*)d_in[6];
    const float* mb1  = (const float*)d_in[7];
    const float* mw2  = (const float*)d_in[8];
    const float* mb2  = (const float*)d_in[9];
    const float* uw1  = (const float*)d_in[10];
    const float* ub1  = (const float*)d_in[11];
    const float* uw2  = (const float*)d_in[12];
    const float* ub2  = (const float*)d_in[13];
    float* h = (float*)d_out;

    int N = in_sizes[3];
    int E = in_sizes[1] / 2;
    int NB = (N + 255) / 256;
    int CB = (E + 255) / 256;

    char* ws = (char*)d_ws;
    size_t o = 0;
    auto alloc = [&](size_t bytes) -> char* {
        char* p = ws + o;
        o += (bytes + 255) & ~(size_t)255;
        return p;
    };
    f16*   t    = (f16*)alloc((size_t)N * 128 * 2);   // tOrg
    f16*   hh   = (f16*)alloc((size_t)N * 128 * 2);
    f16*   tUpd = (f16*)alloc((size_t)N * 128 * 2);
    char*  z0   = (char*)alloc(0);
    int*   degv = (int*)alloc((size_t)N * 4);
    int*   cur  = (int*)alloc((size_t)N * 4);
    int*   dcnt = (int*)alloc(64);
    size_t zbytes = (size_t)((char*)alloc(0) - z0);
    int*   rowp = (int*)alloc((size_t)(N + 1) * 4);
    int*   bsum = (int*)alloc((size_t)NB * 4);
    int2*  esea = (int2*)alloc((size_t)E * 8);
    int4*  recs = (int4*)alloc((size_t)4 * N * 16);
    f16*   pwp  = (f16*)alloc(128 * 128 * 2);
    f16*   mw1p = (f16*)alloc(128 * 128 * 2);
    f16*   mw2p = (f16*)alloc(128 * 128 * 2);
    f16*   uw1p = (f16*)alloc(256 * 128 * 2);
    f16*   uw2p = (f16*)alloc(128 * 128 * 2);

    hipMemsetAsync(z0, 0, zbytes, stream);

    k_prep<<<48 + CB + NB, 256, 0, stream>>>(pw, mw1, mw2, uw1, uw2,
                                             pwp, mw1p, mw2p, uw1p, uw2p,
                                             ei, degv, dep, dcnt, recs, CB, E, N);
    int PB = (N + 63) / 64;
    k_mid<<<NB + PB, 256, 0, stream>>>(degv, bsum, NB, x, pwp, mw1p, pb, mb1,
                                       h, hh, t, N);
    k_scanC<<<NB, 256, 0, stream>>>(degv, bsum, rowp, N, E);
    k_scat<<<CB, 256, 0, stream>>>(ei, eatt, dep, rowp, cur, esea, recs, dcnt, E, N);

    for (int d = 0; d < 4; d++) {
        k_md<<<256, 512, 0, stream>>>(t, tUpd, mw1, mb2, mw2p, esea, recs, dcnt,
                                      hh, uw1p, uw2p, mw1p, ub1, ub2, mb1, h,
                                      d, N);
    }
}

// Round 6
// 465.814 us; speedup vs baseline: 1.0091x; 1.0043x over previous
//
#include <hip/hip_runtime.h>

typedef _Float16 f16;
typedef f16 f16x2 __attribute__((ext_vector_type(2)));
typedef f16 f16x8 __attribute__((ext_vector_type(8)));
typedef float f32x4 __attribute__((ext_vector_type(4)));
typedef float f32x2 __attribute__((ext_vector_type(2)));

#define MFMA16(a, b, c) __builtin_amdgcn_mfma_f32_16x16x32_f16((a), (b), (c), 0, 0, 0)

static __device__ __forceinline__ f16x8 cvt8(const float* __restrict__ p) {
    f32x4 p0 = *(const f32x4*)p;
    f32x4 p1 = *(const f32x4*)(p + 4);
    f16x8 a;
    a[0] = (f16)p0[0]; a[1] = (f16)p0[1]; a[2] = (f16)p0[2]; a[3] = (f16)p0[3];
    a[4] = (f16)p1[0]; a[5] = (f16)p1[1]; a[6] = (f16)p1[2]; a[7] = (f16)p1[3];
    return a;
}

// Fused prep: blocks [0,48) repack weights to B-fragment order; [48,48+CB)
// count in-degrees; rest classify nodes by depth into recs[].x.
__global__ __launch_bounds__(256) void k_prep(
        const float* __restrict__ pw, const float* __restrict__ mw1,
        const float* __restrict__ mw2, const float* __restrict__ uw1,
        const float* __restrict__ uw2,
        f16* __restrict__ pwp, f16* __restrict__ mw1p, f16* __restrict__ mw2p,
        f16* __restrict__ uw1p, f16* __restrict__ uw2p,
        const int* __restrict__ ei, int* __restrict__ degv,
        const int* __restrict__ dep, int* __restrict__ dcnt,
        int4* __restrict__ recs, int CB, int E, int N) {
    __shared__ int lcnt[4];
    __shared__ int lbase[4];
    int b = blockIdx.x;
    int t = threadIdx.x;
    if (b < 48) {
        const float* W; f16* out; int fb;
        if (b < 8)       { W = pw;  out = pwp;  fb = b; }
        else if (b < 16) { W = mw1; out = mw1p; fb = b - 8; }
        else if (b < 24) { W = mw2; out = mw2p; fb = b - 16; }
        else if (b < 40) { W = uw1; out = uw1p; fb = b - 24; }
        else             { W = uw2; out = uw2p; fb = b - 40; }
        int idx = fb * 256 + t;
        int lane = idx & 63;
        int nt = (idx >> 6) & 7;
        int kt = idx >> 9;
        int colx = lane & 15, quad = lane >> 4;
        f16* o = out + (size_t)idx * 8;
        const float* wb = W + (size_t)(kt * 32 + quad * 8) * 128 + nt * 16 + colx;
#pragma unroll
        for (int j = 0; j < 8; j++) o[j] = (f16)wb[(size_t)j * 128];
    } else if (b < 48 + CB) {
        int e = (b - 48) * 256 + t;
        if (e < E) atomicAdd(&degv[ei[E + e]], 1);
    } else {
        if (t < 4) lcnt[t] = 0;
        __syncthreads();
        int v = (b - 48 - CB) * 256 + t;
        int d = (v < N) ? dep[v] : 0;
        int p = -1;
        if (d >= 1 && d <= 4) p = atomicAdd(&lcnt[d - 1], 1);
        __syncthreads();
        if (t < 4) lbase[t] = (lcnt[t] > 0) ? atomicAdd(&dcnt[t], lcnt[t]) : 0;
        __syncthreads();
        if (d >= 1 && d <= 4) recs[(size_t)(d - 1) * N + lbase[d - 1] + p].x = v;
    }
}

// Blocks [0,SB): scan stage A. Rest: proj — h = x@pw+pb (f32 out + f16 shadow
// hh); t = h@mw1[0:128]+mb1.
__global__ __launch_bounds__(256) void k_mid(
        const int* __restrict__ degv, int* __restrict__ bsum, int SB,
        const float* __restrict__ x, const f16* __restrict__ pwp,
        const f16* __restrict__ mw1p, const float* __restrict__ pb,
        const float* __restrict__ mb1, float* __restrict__ h,
        f16* __restrict__ hh, f16* __restrict__ t, int N) {
    __shared__ __align__(16) f16 lds[4][16 * 136];
    __shared__ int wsum[4];
    int tid = threadIdx.x;
    if ((int)blockIdx.x < SB) {
        int idx = blockIdx.x * 256 + tid;
        int v = (idx < N) ? degv[idx] : 0;
#pragma unroll
        for (int off = 32; off; off >>= 1) v += __shfl_down(v, off, 64);
        if ((tid & 63) == 0) wsum[tid >> 6] = v;
        __syncthreads();
        if (tid == 0) bsum[blockIdx.x] = wsum[0] + wsum[1] + wsum[2] + wsum[3];
        return;
    }
    int lane = tid & 63, w = tid >> 6;
    int colx = lane & 15, quad = lane >> 4;
    int base = ((blockIdx.x - SB) * 4 + w) * 16;
    int arow = base + colx;
    int u = arow < N ? arow : N - 1;

    f32x4 c1[8];
#pragma unroll
    for (int nt = 0; nt < 8; nt++) c1[nt] = (f32x4){0.f, 0.f, 0.f, 0.f};
#pragma unroll
    for (int kt = 0; kt < 4; kt++) {
        f16x8 a = cvt8(x + (size_t)u * 128 + kt * 32 + quad * 8);
#pragma unroll
        for (int nt = 0; nt < 8; nt++) {
            f16x8 b = *(const f16x8*)(pwp + ((size_t)(kt * 8 + nt) * 64 + lane) * 8);
            c1[nt] = MFMA16(a, b, c1[nt]);
        }
    }
#pragma unroll
    for (int nt = 0; nt < 8; nt++) {
        float bias = pb[nt * 16 + colx];
#pragma unroll
        for (int reg = 0; reg < 4; reg++) {
            int row = quad * 4 + reg;
            int node = base + row;
            float v = c1[nt][reg] + bias;
            lds[w][row * 136 + nt * 16 + colx] = (f16)v;
            if (node < N) {
                h[(size_t)node * 128 + nt * 16 + colx] = v;
                hh[(size_t)node * 128 + nt * 16 + colx] = (f16)v;
            }
        }
    }
    f32x4 c2[8];
#pragma unroll
    for (int nt = 0; nt < 8; nt++) c2[nt] = (f32x4){0.f, 0.f, 0.f, 0.f};
#pragma unroll
    for (int kt = 0; kt < 4; kt++) {
        f16x8 a = *(const f16x8*)&lds[w][colx * 136 + kt * 32 + quad * 8];
#pragma unroll
        for (int nt = 0; nt < 8; nt++) {
            f16x8 b = *(const f16x8*)(mw1p + ((size_t)(kt * 8 + nt) * 64 + lane) * 8);
            c2[nt] = MFMA16(a, b, c2[nt]);
        }
    }
#pragma unroll
    for (int nt = 0; nt < 8; nt++) {
        float bias = mb1[nt * 16 + colx];
#pragma unroll
        for (int reg = 0; reg < 4; reg++) {
            int node = base + quad * 4 + reg;
            if (node < N) t[(size_t)node * 128 + nt * 16 + colx] = (f16)(c2[nt][reg] + bias);
        }
    }
}

__global__ __launch_bounds__(256) void k_scanC(const int* __restrict__ degv,
                                               const int* __restrict__ bsum,
                                               int* __restrict__ rowp, int N, int E) {
    __shared__ int lds[256];
    __shared__ int wo[4];
    int b = blockIdx.x, t = threadIdx.x;
    int idx = b * 256 + t;
    int v = (idx < N) ? degv[idx] : 0;
    lds[t] = v;
    __syncthreads();
#pragma unroll
    for (int d = 1; d < 256; d <<= 1) {
        int u = (t >= d) ? lds[t - d] : 0;
        __syncthreads();
        lds[t] += u;
        __syncthreads();
    }
    int off = 0;
    for (int j = t; j < b; j += 256) off += bsum[j];
#pragma unroll
    for (int o = 32; o; o >>= 1) off += __shfl_down(off, o, 64);
    if ((t & 63) == 0) wo[t >> 6] = off;
    __syncthreads();
    int boff = wo[0] + wo[1] + wo[2] + wo[3];
    if (idx < N) rowp[idx] = boff + lds[t] - v;
    if (b == 0 && t == 0) rowp[N] = E;
}

// Scatter edges into CSR. esea.x packs src | (dep[src] << 20) so the fused
// msg kernel can select tOrg vs tUpd per edge (N < 2^20, dep <= 4 fits).
__global__ __launch_bounds__(256) void k_scat(const int* __restrict__ ei,
                                              const float* __restrict__ eattr,
                                              const int* __restrict__ dep,
                                              const int* __restrict__ rowp,
                                              int* __restrict__ cur,
                                              int2* __restrict__ esea,
                                              int4* __restrict__ recs,
                                              const int* __restrict__ dcnt,
                                              int E, int N) {
    int gtid = blockIdx.x * 256 + threadIdx.x;
    int gsz = gridDim.x * 256;
    for (int e = gtid; e < E; e += gsz) {
        int s = ei[e], d = ei[E + e];
        int p = rowp[d] + atomicAdd(&cur[d], 1);
        esea[p] = (int2){s | (dep[s] << 20), __float_as_int(eattr[e])};
    }
    for (int d4 = 0; d4 < 4; d4++) {
        int cnt = dcnt[d4];
        for (int i = gtid; i < cnt; i += gsz) {
            int4* r = &recs[(size_t)d4 * N + i];
            int u = r->x;
            r->y = rowp[u];
            r->z = rowp[u + 1];
        }
    }
}

// FUSED per-depth kernel, v5: v4 with the burst array DE-DEMOTED.
//
// v3b/v4 counters showed 183 MB HBM traffic/dispatch vs ~22 MB real data,
// IDENTICAL across the launch_bounds A/B (VGPR_Count pinned at 128 both
// runs) -> not pressure spill but scratch DEMOTION of `f16x8 tld[8]`
// (rule #20: ext_vector array defined under one `if (tval)` and used
// under a second one, with a prefetch block between, defeats SROA).
// 625 chunks x 512 thr x 256 B round-trip ~= the observed ~80 MB excess
// each way. Fix: eight NAMED f16x8 registers, straight-line load+commit
// inside a single guarded block. amdgpu_waves_per_eu(2,2) kept (LDS
// already caps at 1 block/CU = 2 waves/EU, so the 256-VGPR ceiling is
// free headroom).
//
// Structure otherwise identical to v4: 512 threads gather ALL staged
// edges (<=16/node, 256 rows x 256 B = 64 KB tbuf) + hh tile in one
// burst; next chunk's esea prefetched across compute (erec). deg>16
// overflow -> per-wave serial tile loop. Masking: stale LDS rows never
// reach an unmasked output (MFMA M-rows independent; quad*4+reg < rem).
__global__ __launch_bounds__(512)
__attribute__((amdgpu_waves_per_eu(2, 2))) void k_md(
        const f16* __restrict__ tOrg, f16* __restrict__ tUpd,
        const float* __restrict__ mw1, const float* __restrict__ mb2,
        const f16* __restrict__ mw2p, const int2* __restrict__ esea,
        const int4* __restrict__ recs, const int* __restrict__ dcnt,
        const f16* __restrict__ hh, const f16* __restrict__ uw1p,
        const f16* __restrict__ uw2p, const f16* __restrict__ mw1p,
        const float* __restrict__ ub1, const float* __restrict__ ub2,
        const float* __restrict__ mb1, float* __restrict__ h,
        int dIdx, int N) {
    __shared__ __align__(16) f16 bsm[128 * 128];    // staged mw2p (32 KB)
    __shared__ __align__(16) f16 tbuf[256 * 136];   // 256 edge rows (68 KB)
    __shared__ __align__(16) f16 hbuf[16 * 136];    // hh tile
    __shared__ __align__(16) f16 pool[16 * 136];    // agg, then c2-out
    __shared__ __align__(16) f16 sout[16 * 136];    // c1-out
    __shared__ int idsA[64], se0A[64], se1A[64];    // super-chunk recs

    const int tid = threadIdx.x;
    const int lane = tid & 63;
    const int w = tid >> 6;                // 0..7
    const int colx = lane & 15, quad = lane >> 4;
    const int cnt = dcnt[dIdx];

    // stage bsm
    {
        const f16x8* s8 = (const f16x8*)mw2p;
        f16x8* d8 = (f16x8*)bsm;
#pragma unroll
        for (int i = 0; i < 4; i++) d8[i * 512 + tid] = s8[i * 512 + tid];
    }

    // per-thread constants
    const float* w1r = mw1 + 128 * 128;
    f16x8 w1h[4];
#pragma unroll
    for (int kt = 0; kt < 4; kt++) {
        f32x4 q0 = *(const f32x4*)(w1r + kt * 32 + quad * 8);
        f32x4 q1 = *(const f32x4*)(w1r + kt * 32 + quad * 8 + 4);
        w1h[kt][0] = (f16)q0[0]; w1h[kt][1] = (f16)q0[1];
        w1h[kt][2] = (f16)q0[2]; w1h[kt][3] = (f16)q0[3];
        w1h[kt][4] = (f16)q1[0]; w1h[kt][5] = (f16)q1[1];
        w1h[kt][6] = (f16)q1[2]; w1h[kt][7] = (f16)q1[3];
    }
    float mb2v[8];
#pragma unroll
    for (int nt = 0; nt < 8; nt++) mb2v[nt] = mb2[nt * 16 + colx];

    // gather-task decomposition (512 threads over 256 rows x 2 halves)
    const int trow = tid & 255;     // chunk row: node*16 + edge slot
    const int thalf = tid >> 8;     // 0/1 -> 128-B half of the t row
    const int tnode = trow >> 4;    // node 0..15 within chunk
    const int tj = trow & 15;       // edge slot 0..15

    const int b = blockIdx.x, nb = gridDim.x;
    const int s0 = (int)((long long)cnt * b / nb);
    const int s1 = (int)((long long)cnt * (b + 1) / nb);

    auto srow = [&](int sv) -> const f16* {
        const f16* tb = ((unsigned)((sv >> 20) - 1) < (unsigned)dIdx) ? tUpd : tOrg;
        return tb + (size_t)(sv & 0xFFFFF) * 128;
    };

    for (int ss = s0; ss < s1; ss += 64) {
        int scc = s1 - ss; if (scc > 64) scc = 64;
        __syncthreads();  // all reads of idsA/se*/tbuf from prior chunks done
        if (tid < 64) {
            if (tid < scc) {
                int4 r = recs[(size_t)dIdx * N + ss + tid];
                idsA[tid] = r.x; se0A[tid] = r.y; se1A[tid] = r.z;
            } else {
                idsA[tid] = 0; se0A[tid] = 0; se1A[tid] = 0;
            }
        }
        __syncthreads();
        int nch = (scc + 15) >> 4;

        // prefetch first chunk's edge record
        int2 erec = (int2){0, 0};
        {
            int d0 = se1A[tnode] - se0A[tnode];
            if (tj < d0) erec = esea[se0A[tnode] + tj];
        }

        for (int ci = 0; ci < nch; ci++) {
            int cc = scc - ci * 16; if (cc > 16) cc = 16;
            int gidx = ci * 16 + tnode;
            int deg = se1A[gidx] - se0A[gidx];
            bool tval = (tj < deg);
            // ---- issue t-row burst: 8 NAMED f16x8 regs (no array ->
            // no scratch demotion), straight-line loads then commits.
            f16x8 tl0, tl1, tl2, tl3, tl4, tl5, tl6, tl7;
            const f16* tr = nullptr;
            if (tval) {
                tr = srow(erec.x) + thalf * 64;
                tl0 = *(const f16x8*)(tr + 0);
                tl1 = *(const f16x8*)(tr + 8);
                tl2 = *(const f16x8*)(tr + 16);
                tl3 = *(const f16x8*)(tr + 24);
                tl4 = *(const f16x8*)(tr + 32);
                tl5 = *(const f16x8*)(tr + 40);
                tl6 = *(const f16x8*)(tr + 48);
                tl7 = *(const f16x8*)(tr + 56);
            }
            // ---- issue hh burst
            f16x8 hld;
            if (tid < 256) {
                int hrow = tid >> 4, hseg = tid & 15;
                hld = *(const f16x8*)(hh + (size_t)idsA[ci * 16 + hrow] * 128 + hseg * 8);
            }
            // ---- prefetch next chunk's edge record (in flight across compute)
            int2 erecN = (int2){0, 0};
            if (ci + 1 < nch) {
                int g2 = (ci + 1) * 16 + tnode;
                int d2 = se1A[g2] - se0A[g2];
                if (tj < d2) erecN = esea[se0A[g2] + tj];
            }
            // ---- commit bursts to LDS
            if (tval) {
                f16* dst = &tbuf[trow * 136 + thalf * 64];
                *(f16x8*)(dst + 0) = tl0;
                *(f16x8*)(dst + 8) = tl1;
                *(f16x8*)(dst + 16) = tl2;
                *(f16x8*)(dst + 24) = tl3;
                *(f16x8*)(dst + 32) = tl4;
                *(f16x8*)(dst + 40) = tl5;
                *(f16x8*)(dst + 48) = tl6;
                *(f16x8*)(dst + 56) = tl7;
                if (thalf == 0) tbuf[trow * 136 + 128] = (f16)__int_as_float(erec.y);
            }
            if (tid < 256) {
                int hrow = tid >> 4, hseg = tid & 15;
                *(f16x8*)&hbuf[hrow * 136 + hseg * 8] = hld;
            }
            __syncthreads();

            // ---- msg compute: wave w handles nodes 2w, 2w+1
#pragma unroll
            for (int nn = 0; nn < 2; nn++) {
                int n = 2 * w + nn;
                int gi = ci * 16 + n;
                int nd = se1A[gi] - se0A[gi];
                float aggv[8] = {0.f, 0.f, 0.f, 0.f, 0.f, 0.f, 0.f, 0.f};
                if (nd > 0) {
                    // staged tile from tbuf
                    f16 eah = tbuf[(n * 16 + colx) * 136 + 128];
                    f16x8 afr[4];
#pragma unroll
                    for (int kt = 0; kt < 4; kt++) {
                        f16x8 v = *(const f16x8*)&tbuf[(n * 16 + colx) * 136 + kt * 32 + quad * 8];
                        f16x8 o;
#pragma unroll
                        for (int j2 = 0; j2 < 8; j2++) {
                            f16 qv = v[j2] + eah * w1h[kt][j2];
                            o[j2] = qv > (f16)0 ? qv : (f16)0;
                        }
                        afr[kt] = o;
                    }
                    int rem0 = nd < 16 ? nd : 16;
#pragma unroll
                    for (int nt = 0; nt < 8; nt++) {
                        f32x4 c = (f32x4){0.f, 0.f, 0.f, 0.f};
#pragma unroll
                        for (int kt = 0; kt < 4; kt++) {
                            f16x8 bb = *(const f16x8*)&bsm[((kt * 8 + nt) * 64 + lane) * 8];
                            c = MFMA16(afr[kt], bb, c);
                        }
#pragma unroll
                        for (int reg = 0; reg < 4; reg++)
                            if (quad * 4 + reg < rem0)
                                aggv[nt] += fmaxf(c[reg] + mb2v[nt], 0.f);
                    }
                    // overflow tiles (deg > 16): per-wave serial, direct loads
                    for (int bs = 16; bs < nd; bs += 16) {
                        int lim = se1A[gi] - 1;
                        int es = se0A[gi] + bs + colx; if (es > lim) es = lim;
                        int2 er = esea[es];
                        f16 eah2 = (f16)__int_as_float(er.y);
                        const f16* trw = srow(er.x);
                        f16x8 af2[4];
#pragma unroll
                        for (int kt = 0; kt < 4; kt++) {
                            f16x8 v = *(const f16x8*)(trw + kt * 32 + quad * 8);
                            f16x8 o;
#pragma unroll
                            for (int j2 = 0; j2 < 8; j2++) {
                                f16 qv = v[j2] + eah2 * w1h[kt][j2];
                                o[j2] = qv > (f16)0 ? qv : (f16)0;
                            }
                            af2[kt] = o;
                        }
                        int rem = nd - bs;
#pragma unroll
                        for (int nt = 0; nt < 8; nt++) {
                            f32x4 c = (f32x4){0.f, 0.f, 0.f, 0.f};
#pragma unroll
                            for (int kt = 0; kt < 4; kt++) {
                                f16x8 bb = *(const f16x8*)&bsm[((kt * 8 + nt) * 64 + lane) * 8];
                                c = MFMA16(af2[kt], bb, c);
                            }
#pragma unroll
                            for (int reg = 0; reg < 4; reg++)
                                if (quad * 4 + reg < rem)
                                    aggv[nt] += fmaxf(c[reg] + mb2v[nt], 0.f);
                        }
                    }
                }
                float inv = 1.f / (float)(nd > 1 ? nd : 1);
#pragma unroll
                for (int nt = 0; nt < 8; nt++) {
                    float s = aggv[nt];
                    s += __shfl_xor(s, 16, 64);
                    s += __shfl_xor(s, 32, 64);
                    if (quad == 0) pool[n * 136 + nt * 16 + colx] = (f16)(s * inv);
                }
            }
            __syncthreads();

            // ---- update phase: wave w owns nt = w.
            // c1: upd_in = [hbuf | pool], K=256
            f32x4 c1 = (f32x4){0.f, 0.f, 0.f, 0.f};
#pragma unroll
            for (int kt = 0; kt < 8; kt++) {
                f16x8 a;
                if (kt < 4)
                    a = *(const f16x8*)&hbuf[colx * 136 + kt * 32 + quad * 8];
                else
                    a = *(const f16x8*)&pool[colx * 136 + (kt - 4) * 32 + quad * 8];
                f16x8 bb = *(const f16x8*)(uw1p + ((size_t)(kt * 8 + w) * 64 + lane) * 8);
                c1 = MFMA16(a, bb, c1);
            }
            {
                float bias = ub1[w * 16 + colx];
#pragma unroll
                for (int reg = 0; reg < 4; reg++) {
                    int row = quad * 4 + reg;
                    sout[row * 136 + w * 16 + colx] = (f16)fmaxf(c1[reg] + bias, 0.f);
                }
            }
            __syncthreads();
            // c2: h_new = relu(sout @ uw2 + ub2) -> pool + global h
            f32x4 c2 = (f32x4){0.f, 0.f, 0.f, 0.f};
#pragma unroll
            for (int kt = 0; kt < 4; kt++) {
                f16x8 a = *(const f16x8*)&sout[colx * 136 + kt * 32 + quad * 8];
                f16x8 bb = *(const f16x8*)(uw2p + ((size_t)(kt * 8 + w) * 64 + lane) * 8);
                c2 = MFMA16(a, bb, c2);
            }
            {
                float bias = ub2[w * 16 + colx];
#pragma unroll
                for (int reg = 0; reg < 4; reg++) {
                    int row = quad * 4 + reg;
                    float v = fmaxf(c2[reg] + bias, 0.f);
                    pool[row * 136 + w * 16 + colx] = (f16)v;
                    if (row < cc)
                        h[(size_t)idsA[ci * 16 + row] * 128 + w * 16 + colx] = v;
                }
            }
            __syncthreads();
            // c3: t recompute for later depths
            if (dIdx < 3) {
                f32x4 c3 = (f32x4){0.f, 0.f, 0.f, 0.f};
#pragma unroll
                for (int kt = 0; kt < 4; kt++) {
                    f16x8 a = *(const f16x8*)&pool[colx * 136 + kt * 32 + quad * 8];
                    f16x8 bb = *(const f16x8*)(mw1p + ((size_t)(kt * 8 + w) * 64 + lane) * 8);
                    c3 = MFMA16(a, bb, c3);
                }
                float bias = mb1[w * 16 + colx];
#pragma unroll
                for (int reg = 0; reg < 4; reg++) {
                    int row = quad * 4 + reg;
                    if (row < cc)
                        tUpd[(size_t)idsA[ci * 16 + row] * 128 + w * 16 + colx] =
                            (f16)(c3[reg] + bias);
                }
            }
            __syncthreads();  // tbuf/hbuf/pool/sout reusable
            erec = erecN;
        }
    }
}

extern "C" void kernel_launch(void* const* d_in, const int* in_sizes, int n_in,
                              void* d_out, int out_size, void* d_ws, size_t ws_size,
                              hipStream_t stream) {
    const float* x    = (const float*)d_in[0];
    const int*   ei   = (const int*)d_in[1];
    const float* eatt = (const float*)d_in[2];
    const int*   dep  = (const int*)d_in[3];
    const float* pw   = (const float*)d_in[4];
    const float* pb   = (const float*)d_in[5];
    const float* mw1  = (const float*)d_in[6];
    const float* mb1  = (const float*)d_in[7];
    const float* mw2  = (const float*)d_in[8];
    const float* mb2  = (const float*)d_in[9];
    const float* uw1  = (const float*)d_in[10];
    const float* ub1  = (const float*)d_in[11];
    const float* uw2  = (const float*)d_in[12];
    const float* ub2  = (const float*)d_in[13];
    float* h = (float*)d_out;

    int N = in_sizes[3];
    int E = in_sizes[1] / 2;
    int NB = (N + 255) / 256;
    int CB = (E + 255) / 256;

    char* ws = (char*)d_ws;
    size_t o = 0;
    auto alloc = [&](size_t bytes) -> char* {
        char* p = ws + o;
        o += (bytes + 255) & ~(size_t)255;
        return p;
    };
    f16*   t    = (f16*)alloc((size_t)N * 128 * 2);   // tOrg
    f16*   hh   = (f16*)alloc((size_t)N * 128 * 2);
    f16*   tUpd = (f16*)alloc((size_t)N * 128 * 2);
    char*  z0   = (char*)alloc(0);
    int*   degv = (int*)alloc((size_t)N * 4);
    int*   cur  = (int*)alloc((size_t)N * 4);
    int*   dcnt = (int*)alloc(64);
    size_t zbytes = (size_t)((char*)alloc(0) - z0);
    int*   rowp = (int*)alloc((size_t)(N + 1) * 4);
    int*   bsum = (int*)alloc((size_t)NB * 4);
    int2*  esea = (int2*)alloc((size_t)E * 8);
    int4*  recs = (int4*)alloc((size_t)4 * N * 16);
    f16*   pwp  = (f16*)alloc(128 * 128 * 2);
    f16*   mw1p = (f16*)alloc(128 * 128 * 2);
    f16*   mw2p = (f16*)alloc(128 * 128 * 2);
    f16*   uw1p = (f16*)alloc(256 * 128 * 2);
    f16*   uw2p = (f16*)alloc(128 * 128 * 2);

    hipMemsetAsync(z0, 0, zbytes, stream);

    k_prep<<<48 + CB + NB, 256, 0, stream>>>(pw, mw1, mw2, uw1, uw2,
                                             pwp, mw1p, mw2p, uw1p, uw2p,
                                             ei, degv, dep, dcnt, recs, CB, E, N);
    int PB = (N + 63) / 64;
    k_mid<<<NB + PB, 256, 0, stream>>>(degv, bsum, NB, x, pwp, mw1p, pb, mb1,
                                       h, hh, t, N);
    k_scanC<<<NB, 256, 0, stream>>>(degv, bsum, rowp, N, E);
    k_scat<<<CB, 256, 0, stream>>>(ei, eatt, dep, rowp, cur, esea, recs, dcnt, E, N);

    for (int d = 0; d < 4; d++) {
        k_md<<<256, 512, 0, stream>>>(t, tUpd, mw1, mb2, mw2p, esea, recs, dcnt,
                                      hh, uw1p, uw2p, mw1p, ub1, ub2, mb1, h,
                                      d, N);
    }
}

// Round 7
// 397.609 us; speedup vs baseline: 1.1822x; 1.1715x over previous
//
#include <hip/hip_runtime.h>

typedef _Float16 f16;
typedef f16 f16x2 __attribute__((ext_vector_type(2)));
typedef f16 f16x8 __attribute__((ext_vector_type(8)));
typedef float f32x4 __attribute__((ext_vector_type(4)));
typedef float f32x2 __attribute__((ext_vector_type(2)));

#define MFMA16(a, b, c) __builtin_amdgcn_mfma_f32_16x16x32_f16((a), (b), (c), 0, 0, 0)

static __device__ __forceinline__ f16x8 cvt8(const float* __restrict__ p) {
    f32x4 p0 = *(const f32x4*)p;
    f32x4 p1 = *(const f32x4*)(p + 4);
    f16x8 a;
    a[0] = (f16)p0[0]; a[1] = (f16)p0[1]; a[2] = (f16)p0[2]; a[3] = (f16)p0[3];
    a[4] = (f16)p1[0]; a[5] = (f16)p1[1]; a[6] = (f16)p1[2]; a[7] = (f16)p1[3];
    return a;
}

// Fused prep: blocks [0,48) repack weights to B-fragment order; [48,48+CB)
// count in-degrees; rest classify nodes by depth into recs[].x.
__global__ __launch_bounds__(256) void k_prep(
        const float* __restrict__ pw, const float* __restrict__ mw1,
        const float* __restrict__ mw2, const float* __restrict__ uw1,
        const float* __restrict__ uw2,
        f16* __restrict__ pwp, f16* __restrict__ mw1p, f16* __restrict__ mw2p,
        f16* __restrict__ uw1p, f16* __restrict__ uw2p,
        const int* __restrict__ ei, int* __restrict__ degv,
        const int* __restrict__ dep, int* __restrict__ dcnt,
        int4* __restrict__ recs, int CB, int E, int N) {
    __shared__ int lcnt[4];
    __shared__ int lbase[4];
    int b = blockIdx.x;
    int t = threadIdx.x;
    if (b < 48) {
        const float* W; f16* out; int fb;
        if (b < 8)       { W = pw;  out = pwp;  fb = b; }
        else if (b < 16) { W = mw1; out = mw1p; fb = b - 8; }
        else if (b < 24) { W = mw2; out = mw2p; fb = b - 16; }
        else if (b < 40) { W = uw1; out = uw1p; fb = b - 24; }
        else             { W = uw2; out = uw2p; fb = b - 40; }
        int idx = fb * 256 + t;
        int lane = idx & 63;
        int nt = (idx >> 6) & 7;
        int kt = idx >> 9;
        int colx = lane & 15, quad = lane >> 4;
        f16* o = out + (size_t)idx * 8;
        const float* wb = W + (size_t)(kt * 32 + quad * 8) * 128 + nt * 16 + colx;
#pragma unroll
        for (int j = 0; j < 8; j++) o[j] = (f16)wb[(size_t)j * 128];
    } else if (b < 48 + CB) {
        int e = (b - 48) * 256 + t;
        if (e < E) atomicAdd(&degv[ei[E + e]], 1);
    } else {
        if (t < 4) lcnt[t] = 0;
        __syncthreads();
        int v = (b - 48 - CB) * 256 + t;
        int d = (v < N) ? dep[v] : 0;
        int p = -1;
        if (d >= 1 && d <= 4) p = atomicAdd(&lcnt[d - 1], 1);
        __syncthreads();
        if (t < 4) lbase[t] = (lcnt[t] > 0) ? atomicAdd(&dcnt[t], lcnt[t]) : 0;
        __syncthreads();
        if (d >= 1 && d <= 4) recs[(size_t)(d - 1) * N + lbase[d - 1] + p].x = v;
    }
}

// Blocks [0,SB): scan stage A. Rest: proj — h = x@pw+pb (f32 out + f16 shadow
// hh); t = h@mw1[0:128]+mb1.
__global__ __launch_bounds__(256) void k_mid(
        const int* __restrict__ degv, int* __restrict__ bsum, int SB,
        const float* __restrict__ x, const f16* __restrict__ pwp,
        const f16* __restrict__ mw1p, const float* __restrict__ pb,
        const float* __restrict__ mb1, float* __restrict__ h,
        f16* __restrict__ hh, f16* __restrict__ t, int N) {
    __shared__ __align__(16) f16 lds[4][16 * 136];
    __shared__ int wsum[4];
    int tid = threadIdx.x;
    if ((int)blockIdx.x < SB) {
        int idx = blockIdx.x * 256 + tid;
        int v = (idx < N) ? degv[idx] : 0;
#pragma unroll
        for (int off = 32; off; off >>= 1) v += __shfl_down(v, off, 64);
        if ((tid & 63) == 0) wsum[tid >> 6] = v;
        __syncthreads();
        if (tid == 0) bsum[blockIdx.x] = wsum[0] + wsum[1] + wsum[2] + wsum[3];
        return;
    }
    int lane = tid & 63, w = tid >> 6;
    int colx = lane & 15, quad = lane >> 4;
    int base = ((blockIdx.x - SB) * 4 + w) * 16;
    int arow = base + colx;
    int u = arow < N ? arow : N - 1;

    f32x4 c1[8];
#pragma unroll
    for (int nt = 0; nt < 8; nt++) c1[nt] = (f32x4){0.f, 0.f, 0.f, 0.f};
#pragma unroll
    for (int kt = 0; kt < 4; kt++) {
        f16x8 a = cvt8(x + (size_t)u * 128 + kt * 32 + quad * 8);
#pragma unroll
        for (int nt = 0; nt < 8; nt++) {
            f16x8 b = *(const f16x8*)(pwp + ((size_t)(kt * 8 + nt) * 64 + lane) * 8);
            c1[nt] = MFMA16(a, b, c1[nt]);
        }
    }
#pragma unroll
    for (int nt = 0; nt < 8; nt++) {
        float bias = pb[nt * 16 + colx];
#pragma unroll
        for (int reg = 0; reg < 4; reg++) {
            int row = quad * 4 + reg;
            int node = base + row;
            float v = c1[nt][reg] + bias;
            lds[w][row * 136 + nt * 16 + colx] = (f16)v;
            if (node < N) {
                h[(size_t)node * 128 + nt * 16 + colx] = v;
                hh[(size_t)node * 128 + nt * 16 + colx] = (f16)v;
            }
        }
    }
    f32x4 c2[8];
#pragma unroll
    for (int nt = 0; nt < 8; nt++) c2[nt] = (f32x4){0.f, 0.f, 0.f, 0.f};
#pragma unroll
    for (int kt = 0; kt < 4; kt++) {
        f16x8 a = *(const f16x8*)&lds[w][colx * 136 + kt * 32 + quad * 8];
#pragma unroll
        for (int nt = 0; nt < 8; nt++) {
            f16x8 b = *(const f16x8*)(mw1p + ((size_t)(kt * 8 + nt) * 64 + lane) * 8);
            c2[nt] = MFMA16(a, b, c2[nt]);
        }
    }
#pragma unroll
    for (int nt = 0; nt < 8; nt++) {
        float bias = mb1[nt * 16 + colx];
#pragma unroll
        for (int reg = 0; reg < 4; reg++) {
            int node = base + quad * 4 + reg;
            if (node < N) t[(size_t)node * 128 + nt * 16 + colx] = (f16)(c2[nt][reg] + bias);
        }
    }
}

__global__ __launch_bounds__(256) void k_scanC(const int* __restrict__ degv,
                                               const int* __restrict__ bsum,
                                               int* __restrict__ rowp, int N, int E) {
    __shared__ int lds[256];
    __shared__ int wo[4];
    int b = blockIdx.x, t = threadIdx.x;
    int idx = b * 256 + t;
    int v = (idx < N) ? degv[idx] : 0;
    lds[t] = v;
    __syncthreads();
#pragma unroll
    for (int d = 1; d < 256; d <<= 1) {
        int u = (t >= d) ? lds[t - d] : 0;
        __syncthreads();
        lds[t] += u;
        __syncthreads();
    }
    int off = 0;
    for (int j = t; j < b; j += 256) off += bsum[j];
#pragma unroll
    for (int o = 32; o; o >>= 1) off += __shfl_down(off, o, 64);
    if ((t & 63) == 0) wo[t >> 6] = off;
    __syncthreads();
    int boff = wo[0] + wo[1] + wo[2] + wo[3];
    if (idx < N) rowp[idx] = boff + lds[t] - v;
    if (b == 0 && t == 0) rowp[N] = E;
}

// Scatter edges into CSR. esea.x packs src | (dep[src] << 20) so the fused
// msg kernel can select tOrg vs tUpd per edge (N < 2^20, dep <= 4 fits).
__global__ __launch_bounds__(256) void k_scat(const int* __restrict__ ei,
                                              const float* __restrict__ eattr,
                                              const int* __restrict__ dep,
                                              const int* __restrict__ rowp,
                                              int* __restrict__ cur,
                                              int2* __restrict__ esea,
                                              int4* __restrict__ recs,
                                              const int* __restrict__ dcnt,
                                              int E, int N) {
    int gtid = blockIdx.x * 256 + threadIdx.x;
    int gsz = gridDim.x * 256;
    for (int e = gtid; e < E; e += gsz) {
        int s = ei[e], d = ei[E + e];
        int p = rowp[d] + atomicAdd(&cur[d], 1);
        esea[p] = (int2){s | (dep[s] << 20), __float_as_int(eattr[e])};
    }
    for (int d4 = 0; d4 < 4; d4++) {
        int cnt = dcnt[d4];
        for (int i = gtid; i < cnt; i += gsz) {
            int4* r = &recs[(size_t)d4 * N + i];
            int u = r->x;
            r->y = rowp[u];
            r->z = rowp[u + 1];
        }
    }
}

// FUSED per-depth kernel, v6 = v2 skeleton + pipelined staging.
//
// v2 (341.9 us total, 47.5 us/dispatch) exposed TWO dependent HBM
// latencies per 16-edge round inside barriers. v3-family (mega-burst,
// 512 thr) fixed the latency but spilled its 128-B/thread burst to
// scratch (FETCH/WRITE 84/95 MB vs 22 MB real; immune to launch_bounds
// and reg-naming) — structural dead end. v6 returns to v2's 256-thread,
// 2-blocks/CU shape and removes the latency serialization with
// register-LIGHT staging:
//   1) ALL 256 esea records of a 16-node chunk staged in ONE cooperative
//      burst (1 load/thread) -> per-round ebuf latency gone.
//   2) tbuf double-buffered across the 4 quarters; each thread ISSUES
//      quarter q+1's t-gather into 4 named f16x8 regs (16 VGPRs) before
//      the barrier, computes quarter q, then COMMITS after the barrier
//      (T14 issue-early/write-late): gather latency hides under the MFMA
//      quarter. One barrier per quarter (was 3 per round).
// hbuf/sout alias the tbuf halves after the msg phase (barrier-separated;
// see inline notes). LDS = 71.3 KB -> 2 blocks/CU. Compute code is v2
// verbatim (tile stride 136 -> 132). deg>16 overflow: v2's serial path.
// Masking: stale tbuf/ebuf rows are MFMA-row-independent and masked by
// (quad*4+reg < rem) before accumulation, as in v2.
__global__ __launch_bounds__(256) void k_md(
        const f16* __restrict__ tOrg, f16* __restrict__ tUpd,
        const float* __restrict__ mw1, const float* __restrict__ mb2,
        const f16* __restrict__ mw2p, const int2* __restrict__ esea,
        const int4* __restrict__ recs, const int* __restrict__ dcnt,
        const f16* __restrict__ hh, const f16* __restrict__ uw1p,
        const f16* __restrict__ uw2p, const f16* __restrict__ mw1p,
        const float* __restrict__ ub1, const float* __restrict__ ub2,
        const float* __restrict__ mb1, float* __restrict__ h,
        int dIdx, int N) {
    __shared__ __align__(16) f16 bsm[128 * 128];       // 32 KB staged mw2p
    __shared__ __align__(16) f16 tbuf[2][4][16][132];  // 33 KB, dbuf quarters
    __shared__ __align__(16) f16 pool[16][132];        // agg, then c2-out
    __shared__ int2 ebuf[16][16];                      // all chunk edge recs
    __shared__ int ids[16], se0[16], se1[16];
    // After the msg phase tbuf is dead; alias (barrier-separated):
    f16* hbuf = &tbuf[0][0][0][0];  // hh tile   [16][132]
    f16* sout = &tbuf[1][0][0][0];  // c1 output [16][132]

    const int tid = threadIdx.x;
    const int lane = tid & 63;
    const int w = tid >> 6;                 // wave 0..3
    const int colx = lane & 15, quad = lane >> 4;
    const int er0 = tid >> 4;               // staging: edge slot (or node)
    const int sg = tid & 15;                // staging: 16-B segment
    const int cnt = dcnt[dIdx];

    // stage bsm
    {
        const f16x8* s8 = (const f16x8*)mw2p;
        f16x8* d8 = (f16x8*)bsm;
        for (int i = tid; i < 2048; i += 256) d8[i] = s8[i];
    }

    const float* w1r = mw1 + 128 * 128;
    f16x8 w1h[4];
#pragma unroll
    for (int kt = 0; kt < 4; kt++) {
        f32x4 q0 = *(const f32x4*)(w1r + kt * 32 + quad * 8);
        f32x4 q1 = *(const f32x4*)(w1r + kt * 32 + quad * 8 + 4);
        w1h[kt][0] = (f16)q0[0]; w1h[kt][1] = (f16)q0[1];
        w1h[kt][2] = (f16)q0[2]; w1h[kt][3] = (f16)q0[3];
        w1h[kt][4] = (f16)q1[0]; w1h[kt][5] = (f16)q1[1];
        w1h[kt][6] = (f16)q1[2]; w1h[kt][7] = (f16)q1[3];
    }
    float mb2v[8];
#pragma unroll
    for (int nt = 0; nt < 8; nt++) mb2v[nt] = mb2[nt * 16 + colx];

    const int b = blockIdx.x, nb = gridDim.x;
    const int s0g = (int)((long long)cnt * b / nb);
    const int s1g = (int)((long long)cnt * (b + 1) / nb);

    auto srow = [&](int sv) -> const f16* {
        const f16* tb = ((unsigned)((sv >> 20) - 1) < (unsigned)dIdx) ? tUpd : tOrg;
        return tb + (size_t)(sv & 0xFFFFF) * 128;
    };

// ISSUE: load quarter qq's (node it) segment for this thread into a named reg.
#define ISSUE1(dst, qq, it)                                                    \
    do {                                                                       \
        int nn_ = (qq) * 4 + (it);                                             \
        if (er0 < se1[nn_] - se0[nn_]) {                                       \
            int sv_ = ebuf[nn_][er0].x;                                        \
            dst = *(const f16x8*)(srow(sv_) + sg * 8);                         \
        }                                                                      \
    } while (0)
// COMMIT: write the staged reg into tbuf[(qq)&1].
#define COMMIT1(src, qq, it)                                                   \
    do {                                                                       \
        int nn_ = (qq) * 4 + (it);                                             \
        if (er0 < se1[nn_] - se0[nn_])                                         \
            *(f16x8*)&tbuf[(qq) & 1][it][er0][sg * 8] = src;                   \
    } while (0)

    __syncthreads();  // bsm ready

    for (int cs = s0g; cs < s1g; cs += 16) {
        int cc = s1g - cs; if (cc > 16) cc = 16;
        // ---- stage recs
        if (tid < 16) {
            if (tid < cc) {
                int4 r = recs[(size_t)dIdx * N + cs + tid];
                ids[tid] = r.x; se0[tid] = r.y; se1[tid] = r.z;
            } else {
                ids[tid] = 0; se0[tid] = 0; se1[tid] = 0;
            }
        }
        __syncthreads();
        // ---- stage ALL chunk edge records in one burst (node er0, slot sg)
        {
            int dg = se1[er0] - se0[er0];
            if (sg < dg) ebuf[er0][sg] = esea[se0[er0] + sg];
        }
        __syncthreads();

        // ---- msg phase: 4 quarters, tbuf ping-pong, issue-early/commit-late
        f16x8 sr0{}, sr1{}, sr2{}, sr3{};
        ISSUE1(sr0, 0, 0); ISSUE1(sr1, 0, 1); ISSUE1(sr2, 0, 2); ISSUE1(sr3, 0, 3);
        for (int q = 0; q < 4; q++) {
            COMMIT1(sr0, q, 0); COMMIT1(sr1, q, 1);
            COMMIT1(sr2, q, 2); COMMIT1(sr3, q, 3);
            if (q < 3) {
                ISSUE1(sr0, q + 1, 0); ISSUE1(sr1, q + 1, 1);
                ISSUE1(sr2, q + 1, 2); ISSUE1(sr3, q + 1, 3);
            }
            __syncthreads();  // tbuf[q&1] visible; loads for q+1 in flight

            // compute: wave w handles node n = q*4 + w (v2 body)
            int n = q * 4 + w;
            int nd = se1[n] - se0[n];
            float aggv[8] = {0.f, 0.f, 0.f, 0.f, 0.f, 0.f, 0.f, 0.f};
            if (nd > 0) {
                f16 eah = (f16)__int_as_float(ebuf[n][colx].y);
                f16x8 afr[4];
#pragma unroll
                for (int kt = 0; kt < 4; kt++) {
                    f16x8 v = *(const f16x8*)&tbuf[q & 1][w][colx][kt * 32 + quad * 8];
                    f16x8 o;
#pragma unroll
                    for (int j2 = 0; j2 < 8; j2++) {
                        f16 qv = v[j2] + eah * w1h[kt][j2];
                        o[j2] = qv > (f16)0 ? qv : (f16)0;
                    }
                    afr[kt] = o;
                }
                int rem0 = nd < 16 ? nd : 16;
#pragma unroll
                for (int nt = 0; nt < 8; nt++) {
                    f32x4 c = (f32x4){0.f, 0.f, 0.f, 0.f};
#pragma unroll
                    for (int kt = 0; kt < 4; kt++) {
                        f16x8 bb = *(const f16x8*)&bsm[((kt * 8 + nt) * 64 + lane) * 8];
                        c = MFMA16(afr[kt], bb, c);
                    }
#pragma unroll
                    for (int reg = 0; reg < 4; reg++)
                        if (quad * 4 + reg < rem0)
                            aggv[nt] += fmaxf(c[reg] + mb2v[nt], 0.f);
                }
                // overflow tiles (deg > 16): per-wave serial, direct loads
                for (int bs = 16; bs < nd; bs += 16) {
                    int lim = se1[n] - 1;
                    int es = se0[n] + bs + colx; if (es > lim) es = lim;
                    int2 er = esea[es];
                    f16 eah2 = (f16)__int_as_float(er.y);
                    const f16* trw = srow(er.x);
                    f16x8 af2[4];
#pragma unroll
                    for (int kt = 0; kt < 4; kt++) {
                        f16x8 v = *(const f16x8*)(trw + kt * 32 + quad * 8);
                        f16x8 o;
#pragma unroll
                        for (int j2 = 0; j2 < 8; j2++) {
                            f16 qv = v[j2] + eah2 * w1h[kt][j2];
                            o[j2] = qv > (f16)0 ? qv : (f16)0;
                        }
                        af2[kt] = o;
                    }
                    int rem = nd - bs;
#pragma unroll
                    for (int nt = 0; nt < 8; nt++) {
                        f32x4 c = (f32x4){0.f, 0.f, 0.f, 0.f};
#pragma unroll
                        for (int kt = 0; kt < 4; kt++) {
                            f16x8 bb = *(const f16x8*)&bsm[((kt * 8 + nt) * 64 + lane) * 8];
                            c = MFMA16(af2[kt], bb, c);
                        }
#pragma unroll
                        for (int reg = 0; reg < 4; reg++)
                            if (quad * 4 + reg < rem)
                                aggv[nt] += fmaxf(c[reg] + mb2v[nt], 0.f);
                    }
                }
            }
            float inv = 1.f / (float)(nd > 1 ? nd : 1);
#pragma unroll
            for (int nt = 0; nt < 8; nt++) {
                float s = aggv[nt];
                s += __shfl_xor(s, 16, 64);
                s += __shfl_xor(s, 32, 64);
                if (quad == 0) pool[n][nt * 16 + colx] = (f16)(s * inv);
            }
            // no trailing barrier: next iteration's COMMIT targets the other
            // tbuf half; its barrier precedes the next compute.
        }
        __syncthreads();  // msg done; tbuf dead -> hbuf/sout aliases safe

        // ---- stage hh tile cooperatively (one 4 KB burst)
        *(f16x8*)&hbuf[er0 * 132 + sg * 8] =
            *(const f16x8*)(hh + (size_t)ids[er0] * 128 + sg * 8);
        __syncthreads();

        // ---- update phase (v2 verbatim, stride 132): wave w owns nt={2w,2w+1}
        f32x4 c1[2];
        c1[0] = (f32x4){0.f, 0.f, 0.f, 0.f};
        c1[1] = (f32x4){0.f, 0.f, 0.f, 0.f};
#pragma unroll
        for (int kt = 0; kt < 8; kt++) {
            f16x8 a;
            if (kt < 4)
                a = *(const f16x8*)&hbuf[colx * 132 + kt * 32 + quad * 8];
            else
                a = *(const f16x8*)&pool[colx][(kt - 4) * 32 + quad * 8];
#pragma unroll
            for (int j = 0; j < 2; j++) {
                int nt = 2 * w + j;
                f16x8 bb = *(const f16x8*)(uw1p + ((size_t)(kt * 8 + nt) * 64 + lane) * 8);
                c1[j] = MFMA16(a, bb, c1[j]);
            }
        }
#pragma unroll
        for (int j = 0; j < 2; j++) {
            int nt = 2 * w + j;
            float bias = ub1[nt * 16 + colx];
#pragma unroll
            for (int reg = 0; reg < 4; reg++) {
                int row = quad * 4 + reg;
                sout[row * 132 + nt * 16 + colx] = (f16)fmaxf(c1[j][reg] + bias, 0.f);
            }
        }
        __syncthreads();
        // c2: h_new = relu(sout @ uw2 + ub2) -> pool + global h
        f32x4 c2[2];
        c2[0] = (f32x4){0.f, 0.f, 0.f, 0.f};
        c2[1] = (f32x4){0.f, 0.f, 0.f, 0.f};
#pragma unroll
        for (int kt = 0; kt < 4; kt++) {
            f16x8 a = *(const f16x8*)&sout[colx * 132 + kt * 32 + quad * 8];
#pragma unroll
            for (int j = 0; j < 2; j++) {
                int nt = 2 * w + j;
                f16x8 bb = *(const f16x8*)(uw2p + ((size_t)(kt * 8 + nt) * 64 + lane) * 8);
                c2[j] = MFMA16(a, bb, c2[j]);
            }
        }
#pragma unroll
        for (int j = 0; j < 2; j++) {
            int nt = 2 * w + j;
            float bias = ub2[nt * 16 + colx];
#pragma unroll
            for (int reg = 0; reg < 4; reg++) {
                int row = quad * 4 + reg;
                float v = fmaxf(c2[j][reg] + bias, 0.f);
                pool[row][nt * 16 + colx] = (f16)v;
                if (row < cc)
                    h[(size_t)ids[row] * 128 + nt * 16 + colx] = v;
            }
        }
        __syncthreads();
        // c3: t recompute for later depths (skip at last depth)
        if (dIdx < 3) {
            f32x4 c3[2];
            c3[0] = (f32x4){0.f, 0.f, 0.f, 0.f};
            c3[1] = (f32x4){0.f, 0.f, 0.f, 0.f};
#pragma unroll
            for (int kt = 0; kt < 4; kt++) {
                f16x8 a = *(const f16x8*)&pool[colx][kt * 32 + quad * 8];
#pragma unroll
                for (int j = 0; j < 2; j++) {
                    int nt = 2 * w + j;
                    f16x8 bb = *(const f16x8*)(mw1p + ((size_t)(kt * 8 + nt) * 64 + lane) * 8);
                    c3[j] = MFMA16(a, bb, c3[j]);
                }
            }
#pragma unroll
            for (int j = 0; j < 2; j++) {
                int nt = 2 * w + j;
                float bias = mb1[nt * 16 + colx];
#pragma unroll
                for (int reg = 0; reg < 4; reg++) {
                    int row = quad * 4 + reg;
                    if (row < cc)
                        tUpd[(size_t)ids[row] * 128 + nt * 16 + colx] =
                            (f16)(c3[j][reg] + bias);
                }
            }
        }
        __syncthreads();  // protect ids/se*/ebuf/pool/tbuf before next chunk
    }
#undef ISSUE1
#undef COMMIT1
}

extern "C" void kernel_launch(void* const* d_in, const int* in_sizes, int n_in,
                              void* d_out, int out_size, void* d_ws, size_t ws_size,
                              hipStream_t stream) {
    const float* x    = (const float*)d_in[0];
    const int*   ei   = (const int*)d_in[1];
    const float* eatt = (const float*)d_in[2];
    const int*   dep  = (const int*)d_in[3];
    const float* pw   = (const float*)d_in[4];
    const float* pb   = (const float*)d_in[5];
    const float* mw1  = (const float*)d_in[6];
    const float* mb1  = (const float*)d_in[7];
    const float* mw2  = (const float*)d_in[8];
    const float* mb2  = (const float*)d_in[9];
    const float* uw1  = (const float*)d_in[10];
    const float* ub1  = (const float*)d_in[11];
    const float* uw2  = (const float*)d_in[12];
    const float* ub2  = (const float*)d_in[13];
    float* h = (float*)d_out;

    int N = in_sizes[3];
    int E = in_sizes[1] / 2;
    int NB = (N + 255) / 256;
    int CB = (E + 255) / 256;

    char* ws = (char*)d_ws;
    size_t o = 0;
    auto alloc = [&](size_t bytes) -> char* {
        char* p = ws + o;
        o += (bytes + 255) & ~(size_t)255;
        return p;
    };
    f16*   t    = (f16*)alloc((size_t)N * 128 * 2);   // tOrg
    f16*   hh   = (f16*)alloc((size_t)N * 128 * 2);
    f16*   tUpd = (f16*)alloc((size_t)N * 128 * 2);
    char*  z0   = (char*)alloc(0);
    int*   degv = (int*)alloc((size_t)N * 4);
    int*   cur  = (int*)alloc((size_t)N * 4);
    int*   dcnt = (int*)alloc(64);
    size_t zbytes = (size_t)((char*)alloc(0) - z0);
    int*   rowp = (int*)alloc((size_t)(N + 1) * 4);
    int*   bsum = (int*)alloc((size_t)NB * 4);
    int2*  esea = (int2*)alloc((size_t)E * 8);
    int4*  recs = (int4*)alloc((size_t)4 * N * 16);
    f16*   pwp  = (f16*)alloc(128 * 128 * 2);
    f16*   mw1p = (f16*)alloc(128 * 128 * 2);
    f16*   mw2p = (f16*)alloc(128 * 128 * 2);
    f16*   uw1p = (f16*)alloc(256 * 128 * 2);
    f16*   uw2p = (f16*)alloc(128 * 128 * 2);

    hipMemsetAsync(z0, 0, zbytes, stream);

    k_prep<<<48 + CB + NB, 256, 0, stream>>>(pw, mw1, mw2, uw1, uw2,
                                             pwp, mw1p, mw2p, uw1p, uw2p,
                                             ei, degv, dep, dcnt, recs, CB, E, N);
    int PB = (N + 63) / 64;
    k_mid<<<NB + PB, 256, 0, stream>>>(degv, bsum, NB, x, pwp, mw1p, pb, mb1,
                                       h, hh, t, N);
    k_scanC<<<NB, 256, 0, stream>>>(degv, bsum, rowp, N, E);
    k_scat<<<CB, 256, 0, stream>>>(ei, eatt, dep, rowp, cur, esea, recs, dcnt, E, N);

    for (int d = 0; d < 4; d++) {
        k_md<<<512, 256, 0, stream>>>(t, tUpd, mw1, mb2, mw2p, esea, recs, dcnt,
                                      hh, uw1p, uw2p, mw1p, ub1, ub2, mb1, h,
                                      d, N);
    }
}

// Round 8
// 345.690 us; speedup vs baseline: 1.3598x; 1.1502x over previous
//
#include <hip/hip_runtime.h>

typedef _Float16 f16;
typedef f16 f16x2 __attribute__((ext_vector_type(2)));
typedef f16 f16x8 __attribute__((ext_vector_type(8)));
typedef float f32x4 __attribute__((ext_vector_type(4)));
typedef float f32x2 __attribute__((ext_vector_type(2)));

#define MFMA16(a, b, c) __builtin_amdgcn_mfma_f32_16x16x32_f16((a), (b), (c), 0, 0, 0)

static __device__ __forceinline__ f16x8 cvt8(const float* __restrict__ p) {
    f32x4 p0 = *(const f32x4*)p;
    f32x4 p1 = *(const f32x4*)(p + 4);
    f16x8 a;
    a[0] = (f16)p0[0]; a[1] = (f16)p0[1]; a[2] = (f16)p0[2]; a[3] = (f16)p0[3];
    a[4] = (f16)p1[0]; a[5] = (f16)p1[1]; a[6] = (f16)p1[2]; a[7] = (f16)p1[3];
    return a;
}

// Fused prep: blocks [0,48) repack weights to B-fragment order; [48,48+CB)
// count in-degrees; rest classify nodes by depth into recs[].x.
__global__ __launch_bounds__(256) void k_prep(
        const float* __restrict__ pw, const float* __restrict__ mw1,
        const float* __restrict__ mw2, const float* __restrict__ uw1,
        const float* __restrict__ uw2,
        f16* __restrict__ pwp, f16* __restrict__ mw1p, f16* __restrict__ mw2p,
        f16* __restrict__ uw1p, f16* __restrict__ uw2p,
        const int* __restrict__ ei, int* __restrict__ degv,
        const int* __restrict__ dep, int* __restrict__ dcnt,
        int4* __restrict__ recs, int CB, int E, int N) {
    __shared__ int lcnt[4];
    __shared__ int lbase[4];
    int b = blockIdx.x;
    int t = threadIdx.x;
    if (b < 48) {
        const float* W; f16* out; int fb;
        if (b < 8)       { W = pw;  out = pwp;  fb = b; }
        else if (b < 16) { W = mw1; out = mw1p; fb = b - 8; }
        else if (b < 24) { W = mw2; out = mw2p; fb = b - 16; }
        else if (b < 40) { W = uw1; out = uw1p; fb = b - 24; }
        else             { W = uw2; out = uw2p; fb = b - 40; }
        int idx = fb * 256 + t;
        int lane = idx & 63;
        int nt = (idx >> 6) & 7;
        int kt = idx >> 9;
        int colx = lane & 15, quad = lane >> 4;
        f16* o = out + (size_t)idx * 8;
        const float* wb = W + (size_t)(kt * 32 + quad * 8) * 128 + nt * 16 + colx;
#pragma unroll
        for (int j = 0; j < 8; j++) o[j] = (f16)wb[(size_t)j * 128];
    } else if (b < 48 + CB) {
        int e = (b - 48) * 256 + t;
        if (e < E) atomicAdd(&degv[ei[E + e]], 1);
    } else {
        if (t < 4) lcnt[t] = 0;
        __syncthreads();
        int v = (b - 48 - CB) * 256 + t;
        int d = (v < N) ? dep[v] : 0;
        int p = -1;
        if (d >= 1 && d <= 4) p = atomicAdd(&lcnt[d - 1], 1);
        __syncthreads();
        if (t < 4) lbase[t] = (lcnt[t] > 0) ? atomicAdd(&dcnt[t], lcnt[t]) : 0;
        __syncthreads();
        if (d >= 1 && d <= 4) recs[(size_t)(d - 1) * N + lbase[d - 1] + p].x = v;
    }
}

// Blocks [0,SB): scan stage A. Rest: proj — h = x@pw+pb (f32 out + f16 shadow
// hh); t = h@mw1[0:128]+mb1.
__global__ __launch_bounds__(256) void k_mid(
        const int* __restrict__ degv, int* __restrict__ bsum, int SB,
        const float* __restrict__ x, const f16* __restrict__ pwp,
        const f16* __restrict__ mw1p, const float* __restrict__ pb,
        const float* __restrict__ mb1, float* __restrict__ h,
        f16* __restrict__ hh, f16* __restrict__ t, int N) {
    __shared__ __align__(16) f16 lds[4][16 * 136];
    __shared__ int wsum[4];
    int tid = threadIdx.x;
    if ((int)blockIdx.x < SB) {
        int idx = blockIdx.x * 256 + tid;
        int v = (idx < N) ? degv[idx] : 0;
#pragma unroll
        for (int off = 32; off; off >>= 1) v += __shfl_down(v, off, 64);
        if ((tid & 63) == 0) wsum[tid >> 6] = v;
        __syncthreads();
        if (tid == 0) bsum[blockIdx.x] = wsum[0] + wsum[1] + wsum[2] + wsum[3];
        return;
    }
    int lane = tid & 63, w = tid >> 6;
    int colx = lane & 15, quad = lane >> 4;
    int base = ((blockIdx.x - SB) * 4 + w) * 16;
    int arow = base + colx;
    int u = arow < N ? arow : N - 1;

    f32x4 c1[8];
#pragma unroll
    for (int nt = 0; nt < 8; nt++) c1[nt] = (f32x4){0.f, 0.f, 0.f, 0.f};
#pragma unroll
    for (int kt = 0; kt < 4; kt++) {
        f16x8 a = cvt8(x + (size_t)u * 128 + kt * 32 + quad * 8);
#pragma unroll
        for (int nt = 0; nt < 8; nt++) {
            f16x8 b = *(const f16x8*)(pwp + ((size_t)(kt * 8 + nt) * 64 + lane) * 8);
            c1[nt] = MFMA16(a, b, c1[nt]);
        }
    }
#pragma unroll
    for (int nt = 0; nt < 8; nt++) {
        float bias = pb[nt * 16 + colx];
#pragma unroll
        for (int reg = 0; reg < 4; reg++) {
            int row = quad * 4 + reg;
            int node = base + row;
            float v = c1[nt][reg] + bias;
            lds[w][row * 136 + nt * 16 + colx] = (f16)v;
            if (node < N) {
                h[(size_t)node * 128 + nt * 16 + colx] = v;
                hh[(size_t)node * 128 + nt * 16 + colx] = (f16)v;
            }
        }
    }
    f32x4 c2[8];
#pragma unroll
    for (int nt = 0; nt < 8; nt++) c2[nt] = (f32x4){0.f, 0.f, 0.f, 0.f};
#pragma unroll
    for (int kt = 0; kt < 4; kt++) {
        f16x8 a = *(const f16x8*)&lds[w][colx * 136 + kt * 32 + quad * 8];
#pragma unroll
        for (int nt = 0; nt < 8; nt++) {
            f16x8 b = *(const f16x8*)(mw1p + ((size_t)(kt * 8 + nt) * 64 + lane) * 8);
            c2[nt] = MFMA16(a, b, c2[nt]);
        }
    }
#pragma unroll
    for (int nt = 0; nt < 8; nt++) {
        float bias = mb1[nt * 16 + colx];
#pragma unroll
        for (int reg = 0; reg < 4; reg++) {
            int node = base + quad * 4 + reg;
            if (node < N) t[(size_t)node * 128 + nt * 16 + colx] = (f16)(c2[nt][reg] + bias);
        }
    }
}

__global__ __launch_bounds__(256) void k_scanC(const int* __restrict__ degv,
                                               const int* __restrict__ bsum,
                                               int* __restrict__ rowp, int N, int E) {
    __shared__ int lds[256];
    __shared__ int wo[4];
    int b = blockIdx.x, t = threadIdx.x;
    int idx = b * 256 + t;
    int v = (idx < N) ? degv[idx] : 0;
    lds[t] = v;
    __syncthreads();
#pragma unroll
    for (int d = 1; d < 256; d <<= 1) {
        int u = (t >= d) ? lds[t - d] : 0;
        __syncthreads();
        lds[t] += u;
        __syncthreads();
    }
    int off = 0;
    for (int j = t; j < b; j += 256) off += bsum[j];
#pragma unroll
    for (int o = 32; o; o >>= 1) off += __shfl_down(off, o, 64);
    if ((t & 63) == 0) wo[t >> 6] = off;
    __syncthreads();
    int boff = wo[0] + wo[1] + wo[2] + wo[3];
    if (idx < N) rowp[idx] = boff + lds[t] - v;
    if (b == 0 && t == 0) rowp[N] = E;
}

// Scatter edges into CSR. esea.x packs src | (dep[src] << 20) so the fused
// msg kernel can select tOrg vs tUpd per edge (N < 2^20, dep <= 4 fits).
__global__ __launch_bounds__(256) void k_scat(const int* __restrict__ ei,
                                              const float* __restrict__ eattr,
                                              const int* __restrict__ dep,
                                              const int* __restrict__ rowp,
                                              int* __restrict__ cur,
                                              int2* __restrict__ esea,
                                              int4* __restrict__ recs,
                                              const int* __restrict__ dcnt,
                                              int E, int N) {
    int gtid = blockIdx.x * 256 + threadIdx.x;
    int gsz = gridDim.x * 256;
    for (int e = gtid; e < E; e += gsz) {
        int s = ei[e], d = ei[E + e];
        int p = rowp[d] + atomicAdd(&cur[d], 1);
        esea[p] = (int2){s | (dep[s] << 20), __float_as_int(eattr[e])};
    }
    for (int d4 = 0; d4 < 4; d4++) {
        int cnt = dcnt[d4];
        for (int i = gtid; i < cnt; i += gsz) {
            int4* r = &recs[(size_t)d4 * N + i];
            int u = r->x;
            r->y = rowp[u];
            r->z = rowp[u + 1];
        }
    }
}

// FUSED per-depth kernel, v7 = v2 (the 341.9-us best) widened to 8 waves.
//
// v2 ran 2 blocks x 4 waves = 8 waves/CU (VGPR 120 allows 16; LDS was the
// binder). Its cost is per-ROUND serialization (3 barriers + 2 burst
// latencies per 16-KB round). v7 keeps v2's round structure VERBATIM but
// processes 8 nodes per round (32 KB) with 512 threads: rounds/chunk drop
// ~40%, waves/CU double to 16, one bsm copy feeds 8 waves. No new live
// registers across phases (v6's mistake, 188 VGPR -> 2-wave tier). LDS
// 77.5 KB -> 2 blocks/CU. Update phase: wave w owns nt=w (v3b's update,
// refcheck-passed). Masking identical to v2: stale ebuf/tbuf slots only
// feed MFMA rows that are masked by (quad*4+reg < rem) before
// accumulation; chunk-tail rows masked by (row < cc).
__global__ __launch_bounds__(512) void k_md(
        const f16* __restrict__ tOrg, f16* __restrict__ tUpd,
        const float* __restrict__ mw1, const float* __restrict__ mb2,
        const f16* __restrict__ mw2p, const int2* __restrict__ esea,
        const int4* __restrict__ recs, const int* __restrict__ dcnt,
        const f16* __restrict__ hh, const f16* __restrict__ uw1p,
        const f16* __restrict__ uw2p, const f16* __restrict__ mw1p,
        const float* __restrict__ ub1, const float* __restrict__ ub2,
        const float* __restrict__ mb1, float* __restrict__ h,
        int dIdx, int N) {
    __shared__ __align__(16) f16 bsm[128 * 128];     // 32 KB staged mw2p
    __shared__ __align__(16) f16 tbuf[8][16][136];   // 34 KB gathered t rows
    __shared__ __align__(16) f16 pool[16][136];      // agg, then c2-out
    __shared__ __align__(16) f16 sout[16][136];      // c1-out
    __shared__ int2 ebuf[8][16];                     // staged esea records
    __shared__ int ids[16], se0[16], se1[16];
    f16* hbuf = &tbuf[0][0][0];  // hh tile [16][136]; tbuf dead after msg

    const int tid = threadIdx.x;
    const int lane = tid & 63;
    const int w = tid >> 6;                 // wave 0..7
    const int colx = lane & 15, quad = lane >> 4;
    const int cnt = dcnt[dIdx];

    // stage bsm (2048 f16x8 over 512 threads)
    {
        const f16x8* s8 = (const f16x8*)mw2p;
        f16x8* d8 = (f16x8*)bsm;
#pragma unroll
        for (int i = 0; i < 4; i++) d8[i * 512 + tid] = s8[i * 512 + tid];
    }

    const float* w1r = mw1 + 128 * 128;
    f16x8 w1h[4];
#pragma unroll
    for (int kt = 0; kt < 4; kt++) {
        f32x4 q0 = *(const f32x4*)(w1r + kt * 32 + quad * 8);
        f32x4 q1 = *(const f32x4*)(w1r + kt * 32 + quad * 8 + 4);
        w1h[kt][0] = (f16)q0[0]; w1h[kt][1] = (f16)q0[1];
        w1h[kt][2] = (f16)q0[2]; w1h[kt][3] = (f16)q0[3];
        w1h[kt][4] = (f16)q1[0]; w1h[kt][5] = (f16)q1[1];
        w1h[kt][6] = (f16)q1[2]; w1h[kt][7] = (f16)q1[3];
    }
    float mb2v[8];
#pragma unroll
    for (int nt = 0; nt < 8; nt++) mb2v[nt] = mb2[nt * 16 + colx];

    const int b = blockIdx.x, nb = gridDim.x;
    const int s0 = (int)((long long)cnt * b / nb);
    const int s1 = (int)((long long)cnt * (b + 1) / nb);

    auto srow = [&](int sv) -> const f16* {
        const f16* tb = ((unsigned)((sv >> 20) - 1) < (unsigned)dIdx) ? tUpd : tOrg;
        return tb + (size_t)(sv & 0xFFFFF) * 128;
    };

    __syncthreads();  // bsm ready

    for (int cs = s0; cs < s1; cs += 16) {
        int cc = s1 - cs; if (cc > 16) cc = 16;
        // ---- stage recs for the chunk
        if (tid < 16) {
            if (tid < cc) {
                int4 r = recs[(size_t)dIdx * N + cs + tid];
                ids[tid] = r.x; se0[tid] = r.y; se1[tid] = r.z;
            } else {
                ids[tid] = 0; se0[tid] = 0; se1[tid] = 0;
            }
        }
        __syncthreads();

        // ---- msg phase: 2 groups of 8 nodes (v2's quarter loop, widened)
        for (int g = 0; g < 2; g++) {
            int maxT = 0;
#pragma unroll
            for (int s = 0; s < 8; s++) {
                int r = g * 8 + s;
                int tc = (se1[r] - se0[r] + 15) >> 4;
                if (tc > maxT) maxT = tc;
            }
            float aggv[8] = {0.f, 0.f, 0.f, 0.f, 0.f, 0.f, 0.f, 0.f};
            for (int rd = 0; rd < maxT; rd++) {
                // stage esea records for the group's active tiles
                if (tid < 128) {
                    int s = tid >> 4, j = tid & 15;
                    int r = g * 8 + s;
                    int es = se0[r] + rd * 16 + j;
                    if (es < se1[r]) ebuf[s][j] = esea[es];
                }
                __syncthreads();
                // burst-gather t rows: 2048 independent 16B loads
#pragma unroll
                for (int it = 0; it < 4; it++) {
                    int task = it * 512 + tid;
                    int row = task >> 4, seg = task & 15;
                    int s = row >> 4, j = row & 15;
                    int r = g * 8 + s;
                    int es = se0[r] + rd * 16 + j;
                    if (es < se1[r]) {
                        int sv = ebuf[s][j].x;
                        *(f16x8*)&tbuf[s][j][seg * 8] =
                            *(const f16x8*)(srow(sv) + seg * 8);
                    }
                }
                __syncthreads();
                // compute: wave w handles node g*8+w from LDS
                {
                    int r = g * 8 + w;
                    int bs = se0[r] + rd * 16;
                    int rem = se1[r] - bs;
                    if (rem > 0) {
                        f16 eah = (f16)__int_as_float(ebuf[w][colx].y);
                        f16x8 afr[4];
#pragma unroll
                        for (int kt = 0; kt < 4; kt++) {
                            f16x8 v = *(const f16x8*)&tbuf[w][colx][kt * 32 + quad * 8];
                            f16x8 o;
#pragma unroll
                            for (int j2 = 0; j2 < 8; j2++) {
                                f16 qv = v[j2] + eah * w1h[kt][j2];
                                o[j2] = qv > (f16)0 ? qv : (f16)0;
                            }
                            afr[kt] = o;
                        }
#pragma unroll
                        for (int nt = 0; nt < 8; nt++) {
                            f32x4 c = (f32x4){0.f, 0.f, 0.f, 0.f};
#pragma unroll
                            for (int kt = 0; kt < 4; kt++) {
                                f16x8 bb = *(const f16x8*)&bsm[((kt * 8 + nt) * 64 + lane) * 8];
                                c = MFMA16(afr[kt], bb, c);
                            }
#pragma unroll
                            for (int reg = 0; reg < 4; reg++)
                                if (quad * 4 + reg < rem)
                                    aggv[nt] += fmaxf(c[reg] + mb2v[nt], 0.f);
                        }
                    }
                }
                __syncthreads();  // protect ebuf/tbuf before next round
            }
            // mean + write pool row for node g*8+w
            {
                int r = g * 8 + w;
                int deg = se1[r] - se0[r];
                float inv = 1.f / (float)(deg > 1 ? deg : 1);
#pragma unroll
                for (int nt = 0; nt < 8; nt++) {
                    float s = aggv[nt];
                    s += __shfl_xor(s, 16, 64);
                    s += __shfl_xor(s, 32, 64);
                    if (quad == 0) pool[r][nt * 16 + colx] = (f16)(s * inv);
                }
            }
        }
        __syncthreads();  // pool complete; tbuf free for hh staging

        // ---- stage hh tile cooperatively (256 tasks over 512 threads)
        if (tid < 256) {
            int row = tid >> 4, seg = tid & 15;
            *(f16x8*)&hbuf[row * 136 + seg * 8] =
                *(const f16x8*)(hh + (size_t)ids[row] * 128 + seg * 8);
        }
        __syncthreads();

        // ---- update phase: wave w owns nt = w.
        // c1: upd_in = [hbuf | pool], K=256
        f32x4 c1 = (f32x4){0.f, 0.f, 0.f, 0.f};
#pragma unroll
        for (int kt = 0; kt < 8; kt++) {
            f16x8 a;
            if (kt < 4)
                a = *(const f16x8*)&hbuf[colx * 136 + kt * 32 + quad * 8];
            else
                a = *(const f16x8*)&pool[colx][(kt - 4) * 32 + quad * 8];
            f16x8 bb = *(const f16x8*)(uw1p + ((size_t)(kt * 8 + w) * 64 + lane) * 8);
            c1 = MFMA16(a, bb, c1);
        }
        {
            float bias = ub1[w * 16 + colx];
#pragma unroll
            for (int reg = 0; reg < 4; reg++) {
                int row = quad * 4 + reg;
                sout[row][w * 16 + colx] = (f16)fmaxf(c1[reg] + bias, 0.f);
            }
        }
        __syncthreads();
        // c2: h_new = relu(sout @ uw2 + ub2) -> pool + global h
        f32x4 c2 = (f32x4){0.f, 0.f, 0.f, 0.f};
#pragma unroll
        for (int kt = 0; kt < 4; kt++) {
            f16x8 a = *(const f16x8*)&sout[colx][kt * 32 + quad * 8];
            f16x8 bb = *(const f16x8*)(uw2p + ((size_t)(kt * 8 + w) * 64 + lane) * 8);
            c2 = MFMA16(a, bb, c2);
        }
        {
            float bias = ub2[w * 16 + colx];
#pragma unroll
            for (int reg = 0; reg < 4; reg++) {
                int row = quad * 4 + reg;
                float v = fmaxf(c2[reg] + bias, 0.f);
                pool[row][w * 16 + colx] = (f16)v;
                if (row < cc)
                    h[(size_t)ids[row] * 128 + w * 16 + colx] = v;
            }
        }
        __syncthreads();
        // c3: t recompute for later depths (skip at last depth)
        if (dIdx < 3) {
            f32x4 c3 = (f32x4){0.f, 0.f, 0.f, 0.f};
#pragma unroll
            for (int kt = 0; kt < 4; kt++) {
                f16x8 a = *(const f16x8*)&pool[colx][kt * 32 + quad * 8];
                f16x8 bb = *(const f16x8*)(mw1p + ((size_t)(kt * 8 + w) * 64 + lane) * 8);
                c3 = MFMA16(a, bb, c3);
            }
            float bias = mb1[w * 16 + colx];
#pragma unroll
            for (int reg = 0; reg < 4; reg++) {
                int row = quad * 4 + reg;
                if (row < cc)
                    tUpd[(size_t)ids[row] * 128 + w * 16 + colx] =
                        (f16)(c3[reg] + bias);
            }
        }
        __syncthreads();  // protect pool/sout/ids/tbuf before next chunk
    }
}

extern "C" void kernel_launch(void* const* d_in, const int* in_sizes, int n_in,
                              void* d_out, int out_size, void* d_ws, size_t ws_size,
                              hipStream_t stream) {
    const float* x    = (const float*)d_in[0];
    const int*   ei   = (const int*)d_in[1];
    const float* eatt = (const float*)d_in[2];
    const int*   dep  = (const int*)d_in[3];
    const float* pw   = (const float*)d_in[4];
    const float* pb   = (const float*)d_in[5];
    const float* mw1  = (const float*)d_in[6];
    const float* mb1  = (const float*)d_in[7];
    const float* mw2  = (const float*)d_in[8];
    const float* mb2  = (const float*)d_in[9];
    const float* uw1  = (const float*)d_in[10];
    const float* ub1  = (const float*)d_in[11];
    const float* uw2  = (const float*)d_in[12];
    const float* ub2  = (const float*)d_in[13];
    float* h = (float*)d_out;

    int N = in_sizes[3];
    int E = in_sizes[1] / 2;
    int NB = (N + 255) / 256;
    int CB = (E + 255) / 256;

    char* ws = (char*)d_ws;
    size_t o = 0;
    auto alloc = [&](size_t bytes) -> char* {
        char* p = ws + o;
        o += (bytes + 255) & ~(size_t)255;
        return p;
    };
    f16*   t    = (f16*)alloc((size_t)N * 128 * 2);   // tOrg
    f16*   hh   = (f16*)alloc((size_t)N * 128 * 2);
    f16*   tUpd = (f16*)alloc((size_t)N * 128 * 2);
    char*  z0   = (char*)alloc(0);
    int*   degv = (int*)alloc((size_t)N * 4);
    int*   cur  = (int*)alloc((size_t)N * 4);
    int*   dcnt = (int*)alloc(64);
    size_t zbytes = (size_t)((char*)alloc(0) - z0);
    int*   rowp = (int*)alloc((size_t)(N + 1) * 4);
    int*   bsum = (int*)alloc((size_t)NB * 4);
    int2*  esea = (int2*)alloc((size_t)E * 8);
    int4*  recs = (int4*)alloc((size_t)4 * N * 16);
    f16*   pwp  = (f16*)alloc(128 * 128 * 2);
    f16*   mw1p = (f16*)alloc(128 * 128 * 2);
    f16*   mw2p = (f16*)alloc(128 * 128 * 2);
    f16*   uw1p = (f16*)alloc(256 * 128 * 2);
    f16*   uw2p = (f16*)alloc(128 * 128 * 2);

    hipMemsetAsync(z0, 0, zbytes, stream);

    k_prep<<<48 + CB + NB, 256, 0, stream>>>(pw, mw1, mw2, uw1, uw2,
                                             pwp, mw1p, mw2p, uw1p, uw2p,
                                             ei, degv, dep, dcnt, recs, CB, E, N);
    int PB = (N + 63) / 64;
    k_mid<<<NB + PB, 256, 0, stream>>>(degv, bsum, NB, x, pwp, mw1p, pb, mb1,
                                       h, hh, t, N);
    k_scanC<<<NB, 256, 0, stream>>>(degv, bsum, rowp, N, E);
    k_scat<<<CB, 256, 0, stream>>>(ei, eatt, dep, rowp, cur, esea, recs, dcnt, E, N);

    for (int d = 0; d < 4; d++) {
        k_md<<<512, 512, 0, stream>>>(t, tUpd, mw1, mb2, mw2p, esea, recs, dcnt,
                                      hh, uw1p, uw2p, mw1p, ub1, ub2, mb1, h,
                                      d, N);
    }
}